// Round 1
// baseline (4669.183 us; speedup 1.0000x reference)
//
#include <hip/hip_runtime.h>
#include <hip/hip_bf16.h>
#include <math.h>

#define S_LEN 4096
#define D_MODEL 768
#define NHEAD 12
#define DH 64
#define NLAYER 2
#define DFF 3072
#define BATCH 2

// ---------------------------------------------------------------------------
// block-wide reductions (256 threads = 4 waves of 64)
// ---------------------------------------------------------------------------
__device__ __forceinline__ float blk_sum256(float v, float* lds) {
#pragma unroll
  for (int off = 32; off > 0; off >>= 1) v += __shfl_down(v, off, 64);
  __syncthreads();
  if ((threadIdx.x & 63) == 0) lds[threadIdx.x >> 6] = v;
  __syncthreads();
  return lds[0] + lds[1] + lds[2] + lds[3];
}

__device__ __forceinline__ float blk_max256(float v, float* lds) {
#pragma unroll
  for (int off = 32; off > 0; off >>= 1) v = fmaxf(v, __shfl_down(v, off, 64));
  __syncthreads();
  if ((threadIdx.x & 63) == 0) lds[threadIdx.x >> 6] = v;
  __syncthreads();
  return fmaxf(fmaxf(lds[0], lds[1]), fmaxf(lds[2], lds[3]));
}

// ---------------------------------------------------------------------------
// embedding gather + LayerNorm  (one block per row, 256 threads, 768 = 3*256)
// ---------------------------------------------------------------------------
__global__ __launch_bounds__(256) void embed_ln_kernel(
    const int* __restrict__ ids, const float* __restrict__ wemb,
    const float* __restrict__ pemb, const float* __restrict__ g,
    const float* __restrict__ b, float* __restrict__ X) {
  int row = blockIdx.x;                 // b*S + s
  int s = row % S_LEN;
  int id = ids[row];
  const float* we = wemb + (size_t)id * D_MODEL;
  const float* pe = pemb + (size_t)s * D_MODEL;
  int t = threadIdx.x;
  __shared__ float lds[4];
  float v0 = we[t] + pe[t];
  float v1 = we[t + 256] + pe[t + 256];
  float v2 = we[t + 512] + pe[t + 512];
  float mean = blk_sum256(v0 + v1 + v2, lds) * (1.f / 768.f);
  float d0 = v0 - mean, d1 = v1 - mean, d2 = v2 - mean;
  float var = blk_sum256(d0 * d0 + d1 * d1 + d2 * d2, lds) * (1.f / 768.f);
  float rs = rsqrtf(var + 1e-5f);
  float* xp = X + (size_t)row * D_MODEL;
  xp[t]       = d0 * rs * g[t]       + b[t];
  xp[t + 256] = d1 * rs * g[t + 256] + b[t + 256];
  xp[t + 512] = d2 * rs * g[t + 512] + b[t + 512];
}

// ---------------------------------------------------------------------------
// LayerNorm: X = LN(T) * g + b
// ---------------------------------------------------------------------------
__global__ __launch_bounds__(256) void ln_kernel(
    const float* __restrict__ T, const float* __restrict__ g,
    const float* __restrict__ b, float* __restrict__ X) {
  int row = blockIdx.x;
  const float* tp = T + (size_t)row * D_MODEL;
  int t = threadIdx.x;
  __shared__ float lds[4];
  float v0 = tp[t], v1 = tp[t + 256], v2 = tp[t + 512];
  float mean = blk_sum256(v0 + v1 + v2, lds) * (1.f / 768.f);
  float d0 = v0 - mean, d1 = v1 - mean, d2 = v2 - mean;
  float var = blk_sum256(d0 * d0 + d1 * d1 + d2 * d2, lds) * (1.f / 768.f);
  float rs = rsqrtf(var + 1e-5f);
  float* xp = X + (size_t)row * D_MODEL;
  xp[t]       = d0 * rs * g[t]       + b[t];
  xp[t + 256] = d1 * rs * g[t + 256] + b[t + 256];
  xp[t + 512] = d2 * rs * g[t + 512] + b[t + 512];
}

// ---------------------------------------------------------------------------
// fp32 tiled GEMM: C = act(A[MxK] @ W[KxN] + bias) (+ Res)
// BM=BN=64, BK=16, 16x16 threads, 4x4 micro-tile.
// ACT: 0 none, 1 tanh-gelu.  RES: add residual (N must equal Res row length).
// ---------------------------------------------------------------------------
template <int ACT, bool RES>
__global__ __launch_bounds__(256) void gemm_f32(
    const float* __restrict__ A, const float* __restrict__ W,
    const float* __restrict__ bias, const float* __restrict__ Res,
    float* __restrict__ C, int M, int N, int K) {
  __shared__ __align__(16) float As[16][68];   // [k][m]
  __shared__ __align__(16) float Ws[16][68];   // [k][n]
  int tx = threadIdx.x, ty = threadIdx.y;
  int tid = ty * 16 + tx;
  int m0 = blockIdx.y * 64, n0 = blockIdx.x * 64;

  int la_m = tid >> 2;          // 0..63
  int la_k = (tid & 3) * 4;     // 0,4,8,12
  int lw_k = tid >> 4;          // 0..15
  int lw_n = (tid & 15) * 4;    // 0..60

  float acc[4][4] = {{0.f, 0.f, 0.f, 0.f}, {0.f, 0.f, 0.f, 0.f},
                     {0.f, 0.f, 0.f, 0.f}, {0.f, 0.f, 0.f, 0.f}};

  for (int k0 = 0; k0 < K; k0 += 16) {
    float4 a4 = *(const float4*)(A + (size_t)(m0 + la_m) * K + k0 + la_k);
    float4 w4 = *(const float4*)(W + (size_t)(k0 + lw_k) * N + n0 + lw_n);
    __syncthreads();
    As[la_k + 0][la_m] = a4.x;
    As[la_k + 1][la_m] = a4.y;
    As[la_k + 2][la_m] = a4.z;
    As[la_k + 3][la_m] = a4.w;
    *(float4*)&Ws[lw_k][lw_n] = w4;
    __syncthreads();
#pragma unroll
    for (int kk = 0; kk < 16; ++kk) {
      float4 av = *(const float4*)&As[kk][ty * 4];
      float4 wv = *(const float4*)&Ws[kk][tx * 4];
      float aa[4] = {av.x, av.y, av.z, av.w};
      float ww[4] = {wv.x, wv.y, wv.z, wv.w};
#pragma unroll
      for (int i2 = 0; i2 < 4; ++i2)
#pragma unroll
        for (int j2 = 0; j2 < 4; ++j2) acc[i2][j2] += aa[i2] * ww[j2];
    }
  }

#pragma unroll
  for (int i2 = 0; i2 < 4; ++i2) {
    int r = m0 + ty * 4 + i2;
    int cb = n0 + tx * 4;
    float vals[4];
#pragma unroll
    for (int j2 = 0; j2 < 4; ++j2) {
      float v = acc[i2][j2] + bias[cb + j2];
      if (ACT == 1) {
        float x = v;
        float t = tanhf(0.7978845608028654f * (x + 0.044715f * x * x * x));
        v = 0.5f * x * (1.f + t);
      }
      if (RES) v += Res[(size_t)r * N + cb + j2];
      vals[j2] = v;
    }
    *(float4*)(C + (size_t)r * N + cb) = make_float4(vals[0], vals[1], vals[2], vals[3]);
  }
}

// ---------------------------------------------------------------------------
// band (sliding-window) attention + global key, online softmax.
// grid (nc=16, H=12, B=2), block 512: threads = pairs (query i, half of DH).
// Q/K/V layout: [B*S, 768] with head h at columns h*64..h*64+63.
// ---------------------------------------------------------------------------
__global__ __launch_bounds__(512) void band_attn_kernel(
    const float* __restrict__ Q, const float* __restrict__ Kg,
    const float* __restrict__ Vg, const int* __restrict__ att,
    float* __restrict__ Aout) {
  int c = blockIdx.x, h = blockIdx.y, b = blockIdx.z;
  int tid = threadIdx.x;
  int i = tid >> 1;          // query index within chunk (0..255)
  int half = tid & 1;        // which 32 of the 64 dims
  int r = c * 256 + i;       // absolute query row
  __shared__ __align__(16) float Ks[128][64];
  __shared__ __align__(16) float Vs[128][64];
  const size_t bs = (size_t)b * S_LEN;

  float q[32];
  const float* qp = Q + (bs + r) * D_MODEL + h * DH + half * 32;
#pragma unroll
  for (int d = 0; d < 32; d += 4) {
    float4 t4 = *(const float4*)(qp + d);
    q[d] = t4.x * 0.125f; q[d + 1] = t4.y * 0.125f;
    q[d + 2] = t4.z * 0.125f; q[d + 3] = t4.w * 0.125f;
  }

  // global key (position 0): always valid, seeds the online softmax
  const float* kp0 = Kg + bs * D_MODEL + h * DH + half * 32;
  const float* vp0 = Vg + bs * D_MODEL + h * DH + half * 32;
  float accg = 0.f;
#pragma unroll
  for (int d = 0; d < 32; ++d) accg += q[d] * kp0[d];
  accg += __shfl_xor(accg, 1, 64);
  float m = accg, l = 1.f;
  float o[32];
#pragma unroll
  for (int d = 0; d < 32; ++d) o[d] = vp0[d];

  int base = c * 256 - 256;  // key_abs of band position j=0
  for (int tile = 0; tile < 6; ++tile) {
    __syncthreads();
#pragma unroll
    for (int it = 0; it < 4; ++it) {
      int f = tid + it * 512;              // 2048 float4 slots
      int row = f >> 4, c4 = (f & 15) * 4;
      int ka = base + tile * 128 + row;
      float4 kv = make_float4(0.f, 0.f, 0.f, 0.f);
      float4 vv = make_float4(0.f, 0.f, 0.f, 0.f);
      if (ka >= 0 && ka < S_LEN) {
        kv = *(const float4*)(Kg + (bs + ka) * D_MODEL + h * DH + c4);
        vv = *(const float4*)(Vg + (bs + ka) * D_MODEL + h * DH + c4);
      }
      *(float4*)&Ks[row][c4] = kv;
      *(float4*)&Vs[row][c4] = vv;
    }
    __syncthreads();
    for (int sub = 0; sub < 8; ++sub) {
      float s[16];
#pragma unroll
      for (int jj = 0; jj < 16; ++jj) {
        int jl = sub * 16 + jj;
        int j = tile * 128 + jl;
        float a2 = 0.f;
#pragma unroll
        for (int d4 = 0; d4 < 8; ++d4) {
          float4 kv = *(const float4*)&Ks[jl][half * 32 + d4 * 4];
          a2 += q[d4 * 4] * kv.x + q[d4 * 4 + 1] * kv.y +
                q[d4 * 4 + 2] * kv.z + q[d4 * 4 + 3] * kv.w;
        }
        a2 += __shfl_xor(a2, 1, 64);
        int ka = base + j;
        int rel = j - i;
        bool valid = (rel >= 0) && (rel <= 512) && (ka >= 1) && (ka < S_LEN) &&
                     (att[b * S_LEN + ka] > 0);
        s[jj] = valid ? a2 : -1e9f;
      }
      float tmax = s[0];
#pragma unroll
      for (int jj = 1; jj < 16; ++jj) tmax = fmaxf(tmax, s[jj]);
      float mn = fmaxf(m, tmax);
      float sc2 = __expf(m - mn);
      m = mn;
      l *= sc2;
#pragma unroll
      for (int d = 0; d < 32; ++d) o[d] *= sc2;
#pragma unroll
      for (int jj = 0; jj < 16; ++jj) {
        int jl = sub * 16 + jj;
        float p = __expf(s[jj] - m);
        l += p;
#pragma unroll
        for (int d4 = 0; d4 < 8; ++d4) {
          float4 vv = *(const float4*)&Vs[jl][half * 32 + d4 * 4];
          o[d4 * 4]     += p * vv.x;
          o[d4 * 4 + 1] += p * vv.y;
          o[d4 * 4 + 2] += p * vv.z;
          o[d4 * 4 + 3] += p * vv.w;
        }
      }
    }
  }
  float inv = 1.f / l;
  float* op = Aout + (bs + r) * D_MODEL + h * DH + half * 32;
#pragma unroll
  for (int d = 0; d < 32; d += 4) {
    *(float4*)(op + d) = make_float4(o[d] * inv, o[d + 1] * inv,
                                     o[d + 2] * inv, o[d + 3] * inv);
  }
}

// ---------------------------------------------------------------------------
// global row 0 attends to all S keys.  grid (H, B), block 256.
// Runs AFTER band kernel; overwrites row 0 of Aout.
// ---------------------------------------------------------------------------
__global__ __launch_bounds__(256) void global_attn_kernel(
    const float* __restrict__ Q, const float* __restrict__ Kg,
    const float* __restrict__ Vg, const int* __restrict__ att,
    float* __restrict__ Aout) {
  int h = blockIdx.x, b = blockIdx.y;
  int t = threadIdx.x;
  __shared__ float sc[S_LEN];
  __shared__ float q0[64];
  __shared__ float red[4];
  __shared__ float part[4][64];
  const size_t bs = (size_t)b * S_LEN;
  if (t < 64) q0[t] = Q[bs * D_MODEL + h * DH + t] * 0.125f;
  __syncthreads();
  float lmax = -1e30f;
  for (int s = t; s < S_LEN; s += 256) {
    const float* kp = Kg + (bs + s) * D_MODEL + h * DH;
    float acc = 0.f;
#pragma unroll
    for (int d = 0; d < 64; ++d) acc += q0[d] * kp[d];
    acc = (att[b * S_LEN + s] > 0) ? acc : -1e9f;
    sc[s] = acc;
    lmax = fmaxf(lmax, acc);
  }
  float M = blk_max256(lmax, red);
  float lsum = 0.f;
  for (int s = t; s < S_LEN; s += 256) {
    float p = __expf(sc[s] - M);
    sc[s] = p;
    lsum += p;
  }
  float L = blk_sum256(lsum, red);
  int d = t & 63, chunk = t >> 6;
  float acc2 = 0.f;
  for (int s = chunk * 1024; s < (chunk + 1) * 1024; ++s)
    acc2 += sc[s] * Vg[(bs + s) * D_MODEL + h * DH + d];
  part[chunk][d] = acc2;
  __syncthreads();
  if (t < 64) {
    float v = (part[0][t] + part[1][t] + part[2][t] + part[3][t]) / L;
    Aout[bs * D_MODEL + h * DH + t] = v;
  }
}

// ---------------------------------------------------------------------------
// masked mean-pool, two stages
// ---------------------------------------------------------------------------
__global__ __launch_bounds__(256) void pool1_kernel(
    const float* __restrict__ X, const int* __restrict__ att,
    float* __restrict__ ppart) {
  int sb = blockIdx.x, b = blockIdx.y, t = threadIdx.x;
  float a0 = 0.f, a1 = 0.f, a2 = 0.f;
  for (int s = sb * 256; s < sb * 256 + 256; ++s) {
    float a = (float)att[b * S_LEN + s];
    const float* xp = X + ((size_t)b * S_LEN + s) * D_MODEL;
    a0 += xp[t] * a; a1 += xp[t + 256] * a; a2 += xp[t + 512] * a;
  }
  float* pp = ppart + ((size_t)b * 16 + sb) * D_MODEL;
  pp[t] = a0; pp[t + 256] = a1; pp[t + 512] = a2;
}

__global__ __launch_bounds__(256) void pool2_kernel(
    const float* __restrict__ ppart, const int* __restrict__ att,
    float* __restrict__ pooled) {
  int b = blockIdx.x, t = threadIdx.x;
  float a0 = 0.f, a1 = 0.f, a2 = 0.f;
  for (int sb = 0; sb < 16; ++sb) {
    const float* pp = ppart + ((size_t)b * 16 + sb) * D_MODEL;
    a0 += pp[t]; a1 += pp[t + 256]; a2 += pp[t + 512];
  }
  float cnt = 0.f;
  for (int s = 0; s < S_LEN; ++s) cnt += (float)att[b * S_LEN + s];
  cnt = fmaxf(cnt, 1e-9f);
  pooled[b * D_MODEL + t]       = a0 / cnt;
  pooled[b * D_MODEL + t + 256] = a1 / cnt;
  pooled[b * D_MODEL + t + 512] = a2 / cnt;
}

// ---------------------------------------------------------------------------
// head: h = relu(pooled @ Wh1 + bh1); out = sigmoid(h @ Wh2 + bh2) * 4
// one block, 256 threads
// ---------------------------------------------------------------------------
__global__ __launch_bounds__(256) void head_kernel(
    const float* __restrict__ pooled, const float* __restrict__ Wh1,
    const float* __restrict__ bh1, const float* __restrict__ Wh2,
    const float* __restrict__ bh2, float* __restrict__ out) {
  __shared__ float hbuf[2][256];
  int t = threadIdx.x;
  for (int b = 0; b < 2; ++b) {
    float acc = bh1[t];
    for (int d = 0; d < D_MODEL; ++d) acc += pooled[b * D_MODEL + d] * Wh1[d * 256 + t];
    hbuf[b][t] = fmaxf(acc, 0.f);
  }
  __syncthreads();
  if (t < 28) {
    int b = t / 14, j = t % 14;
    float acc = bh2[j];
    for (int i = 0; i < 256; ++i) acc += hbuf[b][i] * Wh2[i * 14 + j];
    out[t] = 4.f / (1.f + __expf(-acc));
  }
}

// ---------------------------------------------------------------------------
static void run_gemm(const float* A, const float* W, const float* bias,
                     const float* Res, float* C, int M, int N, int K, int act,
                     bool res, hipStream_t st) {
  dim3 grid(N / 64, M / 64), block(16, 16);
  if (act == 1)
    gemm_f32<1, false><<<grid, block, 0, st>>>(A, W, bias, nullptr, C, M, N, K);
  else if (res)
    gemm_f32<0, true><<<grid, block, 0, st>>>(A, W, bias, Res, C, M, N, K);
  else
    gemm_f32<0, false><<<grid, block, 0, st>>>(A, W, bias, nullptr, C, M, N, K);
}

extern "C" void kernel_launch(void* const* d_in, const int* in_sizes, int n_in,
                              void* d_out, int out_size, void* d_ws,
                              size_t ws_size, hipStream_t stream) {
  const int* ids    = (const int*)d_in[0];
  const int* att    = (const int*)d_in[1];
  const float* wemb = (const float*)d_in[2];
  const float* pemb = (const float*)d_in[3];
  const float* elng = (const float*)d_in[4];
  const float* elnb = (const float*)d_in[5];
  const float* Wq   = (const float*)d_in[6];
  const float* bq   = (const float*)d_in[7];
  const float* Wk   = (const float*)d_in[8];
  const float* bk   = (const float*)d_in[9];
  const float* Wv   = (const float*)d_in[10];
  const float* bv   = (const float*)d_in[11];
  const float* Wo   = (const float*)d_in[12];
  const float* bo   = (const float*)d_in[13];
  const float* ln1g = (const float*)d_in[14];
  const float* ln1b = (const float*)d_in[15];
  const float* Wf1  = (const float*)d_in[16];
  const float* bf1  = (const float*)d_in[17];
  const float* Wf2  = (const float*)d_in[18];
  const float* bf2  = (const float*)d_in[19];
  const float* ln2g = (const float*)d_in[20];
  const float* ln2b = (const float*)d_in[21];
  const float* Wh1  = (const float*)d_in[22];
  const float* bh1  = (const float*)d_in[23];
  const float* Wh2  = (const float*)d_in[24];
  const float* bh2  = (const float*)d_in[25];

  const int M = BATCH * S_LEN;  // 8192
  float* ws = (float*)d_ws;
  float* X  = ws;                    // 6.29M floats
  float* T  = ws + 6291456;          // 6.29M
  float* Qb = ws + 12582912;         // 6.29M
  float* Kb = ws + 18874368;         // 6.29M
  float* Vb = ws + 25165824;         // 6.29M
  float* Ab = ws + 31457280;         // 6.29M
  float* FF = Qb;                    // 25.17M floats, overlays Q/K/V/A
  float* pooled = ws + 37748736;     // 1536
  float* ppart  = pooled + 2 * D_MODEL;  // 24576

  embed_ln_kernel<<<M, 256, 0, stream>>>(ids, wemb, pemb, elng, elnb, X);

  for (int l = 0; l < NLAYER; ++l) {
    const float* wq = Wq + (size_t)l * D_MODEL * D_MODEL;
    const float* wk = Wk + (size_t)l * D_MODEL * D_MODEL;
    const float* wv = Wv + (size_t)l * D_MODEL * D_MODEL;
    const float* wo = Wo + (size_t)l * D_MODEL * D_MODEL;
    const float* wf1 = Wf1 + (size_t)l * D_MODEL * DFF;
    const float* wf2 = Wf2 + (size_t)l * DFF * D_MODEL;

    run_gemm(X, wq, bq + l * D_MODEL, nullptr, Qb, M, D_MODEL, D_MODEL, 0, false, stream);
    run_gemm(X, wk, bk + l * D_MODEL, nullptr, Kb, M, D_MODEL, D_MODEL, 0, false, stream);
    run_gemm(X, wv, bv + l * D_MODEL, nullptr, Vb, M, D_MODEL, D_MODEL, 0, false, stream);

    band_attn_kernel<<<dim3(16, NHEAD, BATCH), 512, 0, stream>>>(Qb, Kb, Vb, att, Ab);
    global_attn_kernel<<<dim3(NHEAD, BATCH), 256, 0, stream>>>(Qb, Kb, Vb, att, Ab);

    run_gemm(Ab, wo, bo + l * D_MODEL, X, T, M, D_MODEL, D_MODEL, 0, true, stream);
    ln_kernel<<<M, 256, 0, stream>>>(T, ln1g + l * D_MODEL, ln1b + l * D_MODEL, X);

    run_gemm(X, wf1, bf1 + l * DFF, nullptr, FF, M, DFF, D_MODEL, 1, false, stream);
    run_gemm(FF, wf2, bf2 + l * D_MODEL, X, T, M, D_MODEL, DFF, 0, true, stream);
    ln_kernel<<<M, 256, 0, stream>>>(T, ln2g + l * D_MODEL, ln2b + l * D_MODEL, X);
  }

  pool1_kernel<<<dim3(16, BATCH), 256, 0, stream>>>(X, att, ppart);
  pool2_kernel<<<BATCH, 256, 0, stream>>>(ppart, att, pooled);
  head_kernel<<<1, 256, 0, stream>>>(pooled, Wh1, bh1, Wh2, bh2, (float*)d_out);
}

// Round 2
// 2159.322 us; speedup vs baseline: 2.1623x; 2.1623x over previous
//
#include <hip/hip_runtime.h>
#include <hip/hip_bf16.h>
#include <math.h>

#define S_LEN 4096
#define D_MODEL 768
#define NHEAD 12
#define DH 64
#define NLAYER 2
#define DFF 3072
#define BATCH 2

typedef __attribute__((ext_vector_type(8))) __bf16 bf16x8;
typedef __attribute__((ext_vector_type(4))) float f32x4;

// fp32 -> bf16 bits, round-to-nearest-even (finite inputs)
__device__ __forceinline__ unsigned short f2bf_bits(float f) {
  unsigned int u = __float_as_uint(f);
  unsigned int r = (u + 0x7fffu + ((u >> 16) & 1u)) >> 16;
  return (unsigned short)r;
}

#define ASYNC_COPY16(gsrc, ldst)                                       \
  __builtin_amdgcn_global_load_lds(                                    \
      (const __attribute__((address_space(1))) void*)(gsrc),           \
      (__attribute__((address_space(3))) void*)(ldst), 16, 0, 0)

// ---------------------------------------------------------------------------
// block-wide reductions (256 threads = 4 waves of 64)
// ---------------------------------------------------------------------------
__device__ __forceinline__ float blk_sum256(float v, float* lds) {
#pragma unroll
  for (int off = 32; off > 0; off >>= 1) v += __shfl_down(v, off, 64);
  __syncthreads();
  if ((threadIdx.x & 63) == 0) lds[threadIdx.x >> 6] = v;
  __syncthreads();
  return lds[0] + lds[1] + lds[2] + lds[3];
}

__device__ __forceinline__ float blk_max256(float v, float* lds) {
#pragma unroll
  for (int off = 32; off > 0; off >>= 1) v = fmaxf(v, __shfl_down(v, off, 64));
  __syncthreads();
  if ((threadIdx.x & 63) == 0) lds[threadIdx.x >> 6] = v;
  __syncthreads();
  return fmaxf(fmaxf(lds[0], lds[1]), fmaxf(lds[2], lds[3]));
}

// ---------------------------------------------------------------------------
// weight transpose + fp32->bf16 convert: W[K][N] f32 -> Wt[N][K] bf16
// one block per 32x32 tile; grid flattened over all 12 matrices.
// Wbf layout per layer (elems): Wq_t, Wk_t, Wv_t, Wo_t (589824 each),
// Wf1_t (2359296, [3072][768]), Wf2_t (2359296, [768][3072]).
// ---------------------------------------------------------------------------
__global__ __launch_bounds__(256) void wconv_kernel(
    const float* __restrict__ Wq, const float* __restrict__ Wk,
    const float* __restrict__ Wv, const float* __restrict__ Wo,
    const float* __restrict__ Wf1, const float* __restrict__ Wf2,
    unsigned short* __restrict__ Wbf) {
  int id = blockIdx.x;
  const float* src;
  unsigned short* dst;
  int K, N, t;
  if (id < 4608) {                       // Wq/Wk/Wv/Wo, 576 tiles each
    int m = id / 576;
    t = id % 576;
    int layer = m >> 2, which = m & 3;
    const float* s = (which == 0) ? Wq : (which == 1) ? Wk : (which == 2) ? Wv : Wo;
    src = s + (size_t)layer * 589824;
    dst = Wbf + (size_t)layer * 7077888 + (size_t)which * 589824;
    K = 768; N = 768;
  } else if (id < 9216) {                // Wf1 [768][3072]
    int j = id - 4608;
    int layer = j / 2304;
    t = j % 2304;
    src = Wf1 + (size_t)layer * 2359296;
    dst = Wbf + (size_t)layer * 7077888 + 2359296;
    K = 768; N = 3072;
  } else {                               // Wf2 [3072][768]
    int j = id - 9216;
    int layer = j / 2304;
    t = j % 2304;
    src = Wf2 + (size_t)layer * 2359296;
    dst = Wbf + (size_t)layer * 7077888 + 4718592;
    K = 3072; N = 768;
  }
  int tiles_n = N >> 5;
  int tk = t / tiles_n, tn = t % tiles_n;
  __shared__ float tile[32][33];
  int c = threadIdx.x & 31, r0 = threadIdx.x >> 5;
#pragma unroll
  for (int p = 0; p < 4; ++p) {
    int r = r0 + p * 8;
    tile[r][c] = src[(size_t)(tk * 32 + r) * N + tn * 32 + c];
  }
  __syncthreads();
#pragma unroll
  for (int p = 0; p < 4; ++p) {
    int r = r0 + p * 8;  // local n index
    dst[(size_t)(tn * 32 + r) * K + tk * 32 + c] = f2bf_bits(tile[c][r]);
  }
}

// ---------------------------------------------------------------------------
// embedding gather + LayerNorm; writes fp32 X and bf16 Xb
// ---------------------------------------------------------------------------
__global__ __launch_bounds__(256) void embed_ln_kernel(
    const int* __restrict__ ids, const float* __restrict__ wemb,
    const float* __restrict__ pemb, const float* __restrict__ g,
    const float* __restrict__ b, float* __restrict__ X,
    unsigned short* __restrict__ Xb) {
  int row = blockIdx.x;
  int s = row % S_LEN;
  int id = ids[row];
  const float* we = wemb + (size_t)id * D_MODEL;
  const float* pe = pemb + (size_t)s * D_MODEL;
  int t = threadIdx.x;
  __shared__ float lds[4];
  float v0 = we[t] + pe[t];
  float v1 = we[t + 256] + pe[t + 256];
  float v2 = we[t + 512] + pe[t + 512];
  float mean = blk_sum256(v0 + v1 + v2, lds) * (1.f / 768.f);
  float d0 = v0 - mean, d1 = v1 - mean, d2 = v2 - mean;
  float var = blk_sum256(d0 * d0 + d1 * d1 + d2 * d2, lds) * (1.f / 768.f);
  float rs = rsqrtf(var + 1e-5f);
  float o0 = d0 * rs * g[t] + b[t];
  float o1 = d1 * rs * g[t + 256] + b[t + 256];
  float o2 = d2 * rs * g[t + 512] + b[t + 512];
  float* xp = X + (size_t)row * D_MODEL;
  xp[t] = o0; xp[t + 256] = o1; xp[t + 512] = o2;
  unsigned short* xb = Xb + (size_t)row * D_MODEL;
  xb[t] = f2bf_bits(o0); xb[t + 256] = f2bf_bits(o1); xb[t + 512] = f2bf_bits(o2);
}

// ---------------------------------------------------------------------------
// LayerNorm: X = LN(T) * g + b ; writes fp32 X and bf16 Xb
// ---------------------------------------------------------------------------
__global__ __launch_bounds__(256) void ln_kernel(
    const float* __restrict__ T, const float* __restrict__ g,
    const float* __restrict__ b, float* __restrict__ X,
    unsigned short* __restrict__ Xb) {
  int row = blockIdx.x;
  const float* tp = T + (size_t)row * D_MODEL;
  int t = threadIdx.x;
  __shared__ float lds[4];
  float v0 = tp[t], v1 = tp[t + 256], v2 = tp[t + 512];
  float mean = blk_sum256(v0 + v1 + v2, lds) * (1.f / 768.f);
  float d0 = v0 - mean, d1 = v1 - mean, d2 = v2 - mean;
  float var = blk_sum256(d0 * d0 + d1 * d1 + d2 * d2, lds) * (1.f / 768.f);
  float rs = rsqrtf(var + 1e-5f);
  float o0 = d0 * rs * g[t] + b[t];
  float o1 = d1 * rs * g[t + 256] + b[t + 256];
  float o2 = d2 * rs * g[t + 512] + b[t + 512];
  float* xp = X + (size_t)row * D_MODEL;
  xp[t] = o0; xp[t + 256] = o1; xp[t + 512] = o2;
  unsigned short* xb = Xb + (size_t)row * D_MODEL;
  xb[t] = f2bf_bits(o0); xb[t + 256] = f2bf_bits(o1); xb[t + 512] = f2bf_bits(o2);
}

// ---------------------------------------------------------------------------
// bf16 MFMA GEMM: C = epilogue(A[MxK] @ Bt[NxK]^T + bias)
// 128x128 tile, BK=32, 256 threads = 4 waves (2x2), 64x64 per wave,
// v_mfma_f32_16x16x32_bf16, global_load_lds width=16 staging (m97 structure).
// MODE 0: out f32, +bias            (QKV)
// MODE 1: out bf16, +bias, gelu     (FFN1)
// MODE 2: out f32, +bias, +Res f32  (O-proj / FFN2)
// ---------------------------------------------------------------------------
template <int MODE>
__global__ __launch_bounds__(256) void gemm_bf16(
    const unsigned short* __restrict__ A, const unsigned short* __restrict__ Bt,
    const float* __restrict__ bias, const float* __restrict__ Res,
    void* __restrict__ Cout, int M, int N, int K) {
  __shared__ unsigned short Abuf[128 * 32];
  __shared__ unsigned short Bbuf[128 * 32];
  const int tid = threadIdx.x;
  const int lane = tid & 63, w = tid >> 6;
  const int wm = w >> 1, wn = w & 1;
  const int m0 = blockIdx.y * 128, n0 = blockIdx.x * 128;

  f32x4 zero = {0.f, 0.f, 0.f, 0.f};
  f32x4 acc[4][4];
#pragma unroll
  for (int i = 0; i < 4; ++i)
#pragma unroll
    for (int j = 0; j < 4; ++j) acc[i][j] = zero;

  // staging: 512 16B-slots per buffer; wave w instr j covers slots
  // j*256 + w*64 + lane. slot -> row = s>>2, chunk = s&3 (8 bf16 per chunk).
  const int s0 = w * 64 + lane, s1 = 256 + w * 64 + lane;
  const int r0s = s0 >> 2, c0s = s0 & 3;
  const int r1s = s1 >> 2, c1s = s1 & 3;
  const unsigned short* gA0 = A + (size_t)(m0 + r0s) * K + c0s * 8;
  const unsigned short* gA1 = A + (size_t)(m0 + r1s) * K + c1s * 8;
  const unsigned short* gB0 = Bt + (size_t)(n0 + r0s) * K + c0s * 8;
  const unsigned short* gB1 = Bt + (size_t)(n0 + r1s) * K + c1s * 8;
  unsigned short* lA0 = Abuf + (w * 64) * 8;          // wave-uniform bases
  unsigned short* lA1 = Abuf + (256 + w * 64) * 8;
  unsigned short* lB0 = Bbuf + (w * 64) * 8;
  unsigned short* lB1 = Bbuf + (256 + w * 64) * 8;

  // fragment read offsets (elements): A row = lane&15, k-group = lane>>4
  const int frow = lane & 15, kgrp = lane >> 4;
  int aoff[4], boff[4];
#pragma unroll
  for (int i = 0; i < 4; ++i) {
    aoff[i] = (wm * 64 + i * 16 + frow) * 32 + kgrp * 8;
    boff[i] = (wn * 64 + i * 16 + frow) * 32 + kgrp * 8;
  }

  const int nk = K >> 5;
  for (int kt = 0; kt < nk; ++kt) {
    __syncthreads();
    ASYNC_COPY16(gA0, lA0);
    ASYNC_COPY16(gA1, lA1);
    ASYNC_COPY16(gB0, lB0);
    ASYNC_COPY16(gB1, lB1);
    gA0 += 32; gA1 += 32; gB0 += 32; gB1 += 32;
    __syncthreads();
    bf16x8 av[4], bv[4];
#pragma unroll
    for (int i = 0; i < 4; ++i) av[i] = *(const bf16x8*)(Abuf + aoff[i]);
#pragma unroll
    for (int j = 0; j < 4; ++j) bv[j] = *(const bf16x8*)(Bbuf + boff[j]);
#pragma unroll
    for (int i = 0; i < 4; ++i)
#pragma unroll
      for (int j = 0; j < 4; ++j)
        acc[i][j] = __builtin_amdgcn_mfma_f32_16x16x32_bf16(av[i], bv[j],
                                                            acc[i][j], 0, 0, 0);
  }

  // epilogue: C/D layout col = lane&15, row = (lane>>4)*4 + reg
#pragma unroll
  for (int i = 0; i < 4; ++i) {
#pragma unroll
    for (int j = 0; j < 4; ++j) {
      int grb = m0 + wm * 64 + i * 16 + (lane >> 4) * 4;
      int gc = n0 + wn * 64 + j * 16 + (lane & 15);
      float bsv = bias[gc];
#pragma unroll
      for (int r = 0; r < 4; ++r) {
        int gr = grb + r;
        float v = acc[i][j][r] + bsv;
        if (MODE == 1) {
          float x = v;
          float th = tanhf(0.7978845608028654f * (x + 0.044715f * x * x * x));
          v = 0.5f * x * (1.f + th);
        }
        if (MODE == 2) v += Res[(size_t)gr * N + gc];
        if (MODE == 1)
          ((unsigned short*)Cout)[(size_t)gr * N + gc] = f2bf_bits(v);
        else
          ((float*)Cout)[(size_t)gr * N + gc] = v;
      }
    }
  }
}

// ---------------------------------------------------------------------------
// band (sliding-window) attention + global key, online softmax (fp32 math,
// bf16 output). grid (nc=16, H=12, B=2), block 512.
// ---------------------------------------------------------------------------
__global__ __launch_bounds__(512) void band_attn_kernel(
    const float* __restrict__ Q, const float* __restrict__ Kg,
    const float* __restrict__ Vg, const int* __restrict__ att,
    unsigned short* __restrict__ Aout) {
  int c = blockIdx.x, h = blockIdx.y, b = blockIdx.z;
  int tid = threadIdx.x;
  int i = tid >> 1;
  int half = tid & 1;
  int r = c * 256 + i;
  __shared__ __align__(16) float Ks[128][64];
  __shared__ __align__(16) float Vs[128][64];
  const size_t bs = (size_t)b * S_LEN;

  float q[32];
  const float* qp = Q + (bs + r) * D_MODEL + h * DH + half * 32;
#pragma unroll
  for (int d = 0; d < 32; d += 4) {
    float4 t4 = *(const float4*)(qp + d);
    q[d] = t4.x * 0.125f; q[d + 1] = t4.y * 0.125f;
    q[d + 2] = t4.z * 0.125f; q[d + 3] = t4.w * 0.125f;
  }

  const float* kp0 = Kg + bs * D_MODEL + h * DH + half * 32;
  const float* vp0 = Vg + bs * D_MODEL + h * DH + half * 32;
  float accg = 0.f;
#pragma unroll
  for (int d = 0; d < 32; ++d) accg += q[d] * kp0[d];
  accg += __shfl_xor(accg, 1, 64);
  float m = accg, l = 1.f;
  float o[32];
#pragma unroll
  for (int d = 0; d < 32; ++d) o[d] = vp0[d];

  int base = c * 256 - 256;
  for (int tile = 0; tile < 6; ++tile) {
    __syncthreads();
#pragma unroll
    for (int it = 0; it < 4; ++it) {
      int f = tid + it * 512;
      int row = f >> 4, c4 = (f & 15) * 4;
      int ka = base + tile * 128 + row;
      float4 kv = make_float4(0.f, 0.f, 0.f, 0.f);
      float4 vv = make_float4(0.f, 0.f, 0.f, 0.f);
      if (ka >= 0 && ka < S_LEN) {
        kv = *(const float4*)(Kg + (bs + ka) * D_MODEL + h * DH + c4);
        vv = *(const float4*)(Vg + (bs + ka) * D_MODEL + h * DH + c4);
      }
      *(float4*)&Ks[row][c4] = kv;
      *(float4*)&Vs[row][c4] = vv;
    }
    __syncthreads();
    for (int sub = 0; sub < 8; ++sub) {
      float s[16];
#pragma unroll
      for (int jj = 0; jj < 16; ++jj) {
        int jl = sub * 16 + jj;
        int j = tile * 128 + jl;
        float a2 = 0.f;
#pragma unroll
        for (int d4 = 0; d4 < 8; ++d4) {
          float4 kv = *(const float4*)&Ks[jl][half * 32 + d4 * 4];
          a2 += q[d4 * 4] * kv.x + q[d4 * 4 + 1] * kv.y +
                q[d4 * 4 + 2] * kv.z + q[d4 * 4 + 3] * kv.w;
        }
        a2 += __shfl_xor(a2, 1, 64);
        int ka = base + j;
        int rel = j - i;
        bool valid = (rel >= 0) && (rel <= 512) && (ka >= 1) && (ka < S_LEN) &&
                     (att[b * S_LEN + ka] > 0);
        s[jj] = valid ? a2 : -1e9f;
      }
      float tmax = s[0];
#pragma unroll
      for (int jj = 1; jj < 16; ++jj) tmax = fmaxf(tmax, s[jj]);
      float mn = fmaxf(m, tmax);
      float sc2 = __expf(m - mn);
      m = mn;
      l *= sc2;
#pragma unroll
      for (int d = 0; d < 32; ++d) o[d] *= sc2;
#pragma unroll
      for (int jj = 0; jj < 16; ++jj) {
        int jl = sub * 16 + jj;
        float p = __expf(s[jj] - m);
        l += p;
#pragma unroll
        for (int d4 = 0; d4 < 8; ++d4) {
          float4 vv = *(const float4*)&Vs[jl][half * 32 + d4 * 4];
          o[d4 * 4]     += p * vv.x;
          o[d4 * 4 + 1] += p * vv.y;
          o[d4 * 4 + 2] += p * vv.z;
          o[d4 * 4 + 3] += p * vv.w;
        }
      }
    }
  }
  float inv = 1.f / l;
  unsigned short* op = Aout + (bs + r) * D_MODEL + h * DH + half * 32;
#pragma unroll
  for (int d = 0; d < 32; ++d) op[d] = f2bf_bits(o[d] * inv);
}

// ---------------------------------------------------------------------------
// global row 0 attends to all S keys; overwrites row 0 of Aout (bf16).
// ---------------------------------------------------------------------------
__global__ __launch_bounds__(256) void global_attn_kernel(
    const float* __restrict__ Q, const float* __restrict__ Kg,
    const float* __restrict__ Vg, const int* __restrict__ att,
    unsigned short* __restrict__ Aout) {
  int h = blockIdx.x, b = blockIdx.y;
  int t = threadIdx.x;
  __shared__ float sc[S_LEN];
  __shared__ float q0[64];
  __shared__ float red[4];
  __shared__ float part[4][64];
  const size_t bs = (size_t)b * S_LEN;
  if (t < 64) q0[t] = Q[bs * D_MODEL + h * DH + t] * 0.125f;
  __syncthreads();
  float lmax = -1e30f;
  for (int s = t; s < S_LEN; s += 256) {
    const float* kp = Kg + (bs + s) * D_MODEL + h * DH;
    float acc = 0.f;
#pragma unroll
    for (int d = 0; d < 64; ++d) acc += q0[d] * kp[d];
    acc = (att[b * S_LEN + s] > 0) ? acc : -1e9f;
    sc[s] = acc;
    lmax = fmaxf(lmax, acc);
  }
  float M = blk_max256(lmax, red);
  float lsum = 0.f;
  for (int s = t; s < S_LEN; s += 256) {
    float p = __expf(sc[s] - M);
    sc[s] = p;
    lsum += p;
  }
  float L = blk_sum256(lsum, red);
  int d = t & 63, chunk = t >> 6;
  float acc2 = 0.f;
  for (int s = chunk * 1024; s < (chunk + 1) * 1024; ++s)
    acc2 += sc[s] * Vg[(bs + s) * D_MODEL + h * DH + d];
  part[chunk][d] = acc2;
  __syncthreads();
  if (t < 64) {
    float v = (part[0][t] + part[1][t] + part[2][t] + part[3][t]) / L;
    Aout[bs * D_MODEL + h * DH + t] = f2bf_bits(v);
  }
}

// ---------------------------------------------------------------------------
// masked mean-pool, two stages
// ---------------------------------------------------------------------------
__global__ __launch_bounds__(256) void pool1_kernel(
    const float* __restrict__ X, const int* __restrict__ att,
    float* __restrict__ ppart) {
  int sb = blockIdx.x, b = blockIdx.y, t = threadIdx.x;
  float a0 = 0.f, a1 = 0.f, a2 = 0.f;
  for (int s = sb * 256; s < sb * 256 + 256; ++s) {
    float a = (float)att[b * S_LEN + s];
    const float* xp = X + ((size_t)b * S_LEN + s) * D_MODEL;
    a0 += xp[t] * a; a1 += xp[t + 256] * a; a2 += xp[t + 512] * a;
  }
  float* pp = ppart + ((size_t)b * 16 + sb) * D_MODEL;
  pp[t] = a0; pp[t + 256] = a1; pp[t + 512] = a2;
}

__global__ __launch_bounds__(256) void pool2_kernel(
    const float* __restrict__ ppart, const int* __restrict__ att,
    float* __restrict__ pooled) {
  int b = blockIdx.x, t = threadIdx.x;
  float a0 = 0.f, a1 = 0.f, a2 = 0.f;
  for (int sb = 0; sb < 16; ++sb) {
    const float* pp = ppart + ((size_t)b * 16 + sb) * D_MODEL;
    a0 += pp[t]; a1 += pp[t + 256]; a2 += pp[t + 512];
  }
  float cnt = 0.f;
  for (int s = 0; s < S_LEN; ++s) cnt += (float)att[b * S_LEN + s];
  cnt = fmaxf(cnt, 1e-9f);
  pooled[b * D_MODEL + t]       = a0 / cnt;
  pooled[b * D_MODEL + t + 256] = a1 / cnt;
  pooled[b * D_MODEL + t + 512] = a2 / cnt;
}

// ---------------------------------------------------------------------------
// head: h = relu(pooled @ Wh1 + bh1); out = sigmoid(h @ Wh2 + bh2) * 4
// ---------------------------------------------------------------------------
__global__ __launch_bounds__(256) void head_kernel(
    const float* __restrict__ pooled, const float* __restrict__ Wh1,
    const float* __restrict__ bh1, const float* __restrict__ Wh2,
    const float* __restrict__ bh2, float* __restrict__ out) {
  __shared__ float hbuf[2][256];
  int t = threadIdx.x;
  for (int b = 0; b < 2; ++b) {
    float acc = bh1[t];
    for (int d = 0; d < D_MODEL; ++d) acc += pooled[b * D_MODEL + d] * Wh1[d * 256 + t];
    hbuf[b][t] = fmaxf(acc, 0.f);
  }
  __syncthreads();
  if (t < 28) {
    int b = t / 14, j = t % 14;
    float acc = bh2[j];
    for (int i = 0; i < 256; ++i) acc += hbuf[b][i] * Wh2[i * 14 + j];
    out[t] = 4.f / (1.f + __expf(-acc));
  }
}

// ---------------------------------------------------------------------------
static void run_gemm_bf16(const unsigned short* A, const unsigned short* Bt,
                          const float* bias, const float* Res, void* C, int M,
                          int N, int K, int mode, hipStream_t st) {
  dim3 grid(N / 128, M / 128);
  if (mode == 0)
    gemm_bf16<0><<<grid, 256, 0, st>>>(A, Bt, bias, nullptr, C, M, N, K);
  else if (mode == 1)
    gemm_bf16<1><<<grid, 256, 0, st>>>(A, Bt, bias, nullptr, C, M, N, K);
  else
    gemm_bf16<2><<<grid, 256, 0, st>>>(A, Bt, bias, Res, C, M, N, K);
}

extern "C" void kernel_launch(void* const* d_in, const int* in_sizes, int n_in,
                              void* d_out, int out_size, void* d_ws,
                              size_t ws_size, hipStream_t stream) {
  const int* ids    = (const int*)d_in[0];
  const int* att    = (const int*)d_in[1];
  const float* wemb = (const float*)d_in[2];
  const float* pemb = (const float*)d_in[3];
  const float* elng = (const float*)d_in[4];
  const float* elnb = (const float*)d_in[5];
  const float* Wq   = (const float*)d_in[6];
  const float* bq   = (const float*)d_in[7];
  const float* Wk   = (const float*)d_in[8];
  const float* bk   = (const float*)d_in[9];
  const float* Wv   = (const float*)d_in[10];
  const float* bv   = (const float*)d_in[11];
  const float* Wo   = (const float*)d_in[12];
  const float* bo   = (const float*)d_in[13];
  const float* ln1g = (const float*)d_in[14];
  const float* ln1b = (const float*)d_in[15];
  const float* Wf1  = (const float*)d_in[16];
  const float* bf1  = (const float*)d_in[17];
  const float* Wf2  = (const float*)d_in[18];
  const float* bf2  = (const float*)d_in[19];
  const float* ln2g = (const float*)d_in[20];
  const float* ln2b = (const float*)d_in[21];
  const float* Wh1  = (const float*)d_in[22];
  const float* bh1  = (const float*)d_in[23];
  const float* Wh2  = (const float*)d_in[24];
  const float* bh2  = (const float*)d_in[25];

  const int M = BATCH * S_LEN;  // 8192
  float* ws = (float*)d_ws;
  float* X  = ws;                                   // [0, 6.29M)
  float* T  = ws + 6291456;                         // [6.29M, 12.58M)
  float* Qb = ws + 12582912;                        // [12.58M, 18.87M)
  float* Kb = ws + 18874368;                        // [18.87M, 25.17M)
  float* Vb = ws + 25165824;                        // [25.17M, 31.46M)
  unsigned short* FFbf = (unsigned short*)(ws + 12582912);  // overlays Qb+Kb
  unsigned short* Abbf = (unsigned short*)(ws + 31457280);  // 6.29M bf16
  unsigned short* Xbf  = (unsigned short*)(ws + 34603008);  // 6.29M bf16
  unsigned short* Wbf  = (unsigned short*)(ws + 37748736);  // 14.16M bf16
  float* pooled = ws + 44826624;
  float* ppart  = ws + 44828160;

  wconv_kernel<<<13824, 256, 0, stream>>>(Wq, Wk, Wv, Wo, Wf1, Wf2, Wbf);
  embed_ln_kernel<<<M, 256, 0, stream>>>(ids, wemb, pemb, elng, elnb, X, Xbf);

  for (int l = 0; l < NLAYER; ++l) {
    const unsigned short* wqt  = Wbf + (size_t)l * 7077888;
    const unsigned short* wkt  = wqt + 589824;
    const unsigned short* wvt  = wqt + 1179648;
    const unsigned short* wot  = wqt + 1769472;
    const unsigned short* wf1t = wqt + 2359296;
    const unsigned short* wf2t = wqt + 4718592;

    run_gemm_bf16(Xbf, wqt, bq + l * D_MODEL, nullptr, Qb, M, 768, 768, 0, stream);
    run_gemm_bf16(Xbf, wkt, bk + l * D_MODEL, nullptr, Kb, M, 768, 768, 0, stream);
    run_gemm_bf16(Xbf, wvt, bv + l * D_MODEL, nullptr, Vb, M, 768, 768, 0, stream);

    band_attn_kernel<<<dim3(16, NHEAD, BATCH), 512, 0, stream>>>(Qb, Kb, Vb, att, Abbf);
    global_attn_kernel<<<dim3(NHEAD, BATCH), 256, 0, stream>>>(Qb, Kb, Vb, att, Abbf);

    run_gemm_bf16(Abbf, wot, bo + l * D_MODEL, X, T, M, 768, 768, 2, stream);
    ln_kernel<<<M, 256, 0, stream>>>(T, ln1g + l * D_MODEL, ln1b + l * D_MODEL, X, Xbf);

    run_gemm_bf16(Xbf, wf1t, bf1 + l * DFF, nullptr, FFbf, M, DFF, 768, 1, stream);
    run_gemm_bf16(FFbf, wf2t, bf2 + l * D_MODEL, X, T, M, 768, DFF, 2, stream);
    ln_kernel<<<M, 256, 0, stream>>>(T, ln2g + l * D_MODEL, ln2b + l * D_MODEL, X, Xbf);
  }

  pool1_kernel<<<dim3(16, BATCH), 256, 0, stream>>>(X, att, ppart);
  pool2_kernel<<<BATCH, 256, 0, stream>>>(ppart, att, pooled);
  head_kernel<<<1, 256, 0, stream>>>(pooled, Wh1, bh1, Wh2, bh2, (float*)d_out);
}

// Round 3
// 1104.485 us; speedup vs baseline: 4.2275x; 1.9550x over previous
//
#include <hip/hip_runtime.h>
#include <hip/hip_bf16.h>
#include <math.h>

#define S_LEN 4096
#define D_MODEL 768
#define NHEAD 12
#define DH 64
#define NLAYER 2
#define DFF 3072
#define BATCH 2

typedef __attribute__((ext_vector_type(8))) __bf16 bf16x8;
typedef __attribute__((ext_vector_type(4))) float f32x4;

// fp32 -> bf16 bits, round-to-nearest-even (finite inputs)
__device__ __forceinline__ unsigned short f2bf_bits(float f) {
  unsigned int u = __float_as_uint(f);
  unsigned int r = (u + 0x7fffu + ((u >> 16) & 1u)) >> 16;
  return (unsigned short)r;
}

__device__ __forceinline__ float bf2f(unsigned short u) {
  return __uint_as_float(((unsigned int)u) << 16);
}

// pack two f32 into one dword of two bf16 (RNE)
__device__ __forceinline__ unsigned int cvtpk_bf16(float lo, float hi) {
  unsigned int d;
  asm("v_cvt_pk_bf16_f32 %0, %1, %2" : "=v"(d) : "v"(lo), "v"(hi));
  return d;
}

#define ASYNC_COPY16(gsrc, ldst)                                       \
  __builtin_amdgcn_global_load_lds(                                    \
      (const __attribute__((address_space(1))) void*)(gsrc),           \
      (__attribute__((address_space(3))) void*)(ldst), 16, 0, 0)

#define MFMA_BF16(a, b, c) __builtin_amdgcn_mfma_f32_16x16x32_bf16(a, b, c, 0, 0, 0)

// ---------------------------------------------------------------------------
// block-wide reductions (256 threads = 4 waves of 64)
// ---------------------------------------------------------------------------
__device__ __forceinline__ float blk_sum256(float v, float* lds) {
#pragma unroll
  for (int off = 32; off > 0; off >>= 1) v += __shfl_down(v, off, 64);
  __syncthreads();
  if ((threadIdx.x & 63) == 0) lds[threadIdx.x >> 6] = v;
  __syncthreads();
  return lds[0] + lds[1] + lds[2] + lds[3];
}

__device__ __forceinline__ float blk_max256(float v, float* lds) {
#pragma unroll
  for (int off = 32; off > 0; off >>= 1) v = fmaxf(v, __shfl_down(v, off, 64));
  __syncthreads();
  if ((threadIdx.x & 63) == 0) lds[threadIdx.x >> 6] = v;
  __syncthreads();
  return fmaxf(fmaxf(lds[0], lds[1]), fmaxf(lds[2], lds[3]));
}

// ---------------------------------------------------------------------------
// weight transpose + fp32->bf16 convert: W[K][N] f32 -> Wt[N][K] bf16
// ---------------------------------------------------------------------------
__global__ __launch_bounds__(256) void wconv_kernel(
    const float* __restrict__ Wq, const float* __restrict__ Wk,
    const float* __restrict__ Wv, const float* __restrict__ Wo,
    const float* __restrict__ Wf1, const float* __restrict__ Wf2,
    unsigned short* __restrict__ Wbf) {
  int id = blockIdx.x;
  const float* src;
  unsigned short* dst;
  int K, N, t;
  if (id < 4608) {                       // Wq/Wk/Wv/Wo, 576 tiles each
    int m = id / 576;
    t = id % 576;
    int layer = m >> 2, which = m & 3;
    const float* s = (which == 0) ? Wq : (which == 1) ? Wk : (which == 2) ? Wv : Wo;
    src = s + (size_t)layer * 589824;
    dst = Wbf + (size_t)layer * 7077888 + (size_t)which * 589824;
    K = 768; N = 768;
  } else if (id < 9216) {                // Wf1 [768][3072]
    int j = id - 4608;
    int layer = j / 2304;
    t = j % 2304;
    src = Wf1 + (size_t)layer * 2359296;
    dst = Wbf + (size_t)layer * 7077888 + 2359296;
    K = 768; N = 3072;
  } else {                               // Wf2 [3072][768]
    int j = id - 9216;
    int layer = j / 2304;
    t = j % 2304;
    src = Wf2 + (size_t)layer * 2359296;
    dst = Wbf + (size_t)layer * 7077888 + 4718592;
    K = 3072; N = 768;
  }
  int tiles_n = N >> 5;
  int tk = t / tiles_n, tn = t % tiles_n;
  __shared__ float tile[32][33];
  int c = threadIdx.x & 31, r0 = threadIdx.x >> 5;
#pragma unroll
  for (int p = 0; p < 4; ++p) {
    int r = r0 + p * 8;
    tile[r][c] = src[(size_t)(tk * 32 + r) * N + tn * 32 + c];
  }
  __syncthreads();
#pragma unroll
  for (int p = 0; p < 4; ++p) {
    int r = r0 + p * 8;  // local n index
    dst[(size_t)(tn * 32 + r) * K + tk * 32 + c] = f2bf_bits(tile[c][r]);
  }
}

// ---------------------------------------------------------------------------
// embedding gather + LayerNorm; writes fp32 X and bf16 Xb
// ---------------------------------------------------------------------------
__global__ __launch_bounds__(256) void embed_ln_kernel(
    const int* __restrict__ ids, const float* __restrict__ wemb,
    const float* __restrict__ pemb, const float* __restrict__ g,
    const float* __restrict__ b, float* __restrict__ X,
    unsigned short* __restrict__ Xb) {
  int row = blockIdx.x;
  int s = row % S_LEN;
  int id = ids[row];
  const float* we = wemb + (size_t)id * D_MODEL;
  const float* pe = pemb + (size_t)s * D_MODEL;
  int t = threadIdx.x;
  __shared__ float lds[4];
  float v0 = we[t] + pe[t];
  float v1 = we[t + 256] + pe[t + 256];
  float v2 = we[t + 512] + pe[t + 512];
  float mean = blk_sum256(v0 + v1 + v2, lds) * (1.f / 768.f);
  float d0 = v0 - mean, d1 = v1 - mean, d2 = v2 - mean;
  float var = blk_sum256(d0 * d0 + d1 * d1 + d2 * d2, lds) * (1.f / 768.f);
  float rs = rsqrtf(var + 1e-5f);
  float o0 = d0 * rs * g[t] + b[t];
  float o1 = d1 * rs * g[t + 256] + b[t + 256];
  float o2 = d2 * rs * g[t + 512] + b[t + 512];
  float* xp = X + (size_t)row * D_MODEL;
  xp[t] = o0; xp[t + 256] = o1; xp[t + 512] = o2;
  unsigned short* xb = Xb + (size_t)row * D_MODEL;
  xb[t] = f2bf_bits(o0); xb[t + 256] = f2bf_bits(o1); xb[t + 512] = f2bf_bits(o2);
}

// ---------------------------------------------------------------------------
// LayerNorm: X = LN(T) * g + b ; writes fp32 X and bf16 Xb
// ---------------------------------------------------------------------------
__global__ __launch_bounds__(256) void ln_kernel(
    const float* __restrict__ T, const float* __restrict__ g,
    const float* __restrict__ b, float* __restrict__ X,
    unsigned short* __restrict__ Xb) {
  int row = blockIdx.x;
  const float* tp = T + (size_t)row * D_MODEL;
  int t = threadIdx.x;
  __shared__ float lds[4];
  float v0 = tp[t], v1 = tp[t + 256], v2 = tp[t + 512];
  float mean = blk_sum256(v0 + v1 + v2, lds) * (1.f / 768.f);
  float d0 = v0 - mean, d1 = v1 - mean, d2 = v2 - mean;
  float var = blk_sum256(d0 * d0 + d1 * d1 + d2 * d2, lds) * (1.f / 768.f);
  float rs = rsqrtf(var + 1e-5f);
  float o0 = d0 * rs * g[t] + b[t];
  float o1 = d1 * rs * g[t + 256] + b[t + 256];
  float o2 = d2 * rs * g[t + 512] + b[t + 512];
  float* xp = X + (size_t)row * D_MODEL;
  xp[t] = o0; xp[t + 256] = o1; xp[t + 512] = o2;
  unsigned short* xb = Xb + (size_t)row * D_MODEL;
  xb[t] = f2bf_bits(o0); xb[t + 256] = f2bf_bits(o1); xb[t + 512] = f2bf_bits(o2);
}

// ---------------------------------------------------------------------------
// bf16 MFMA GEMM: C = epilogue(A[MxK] @ Bt[NxK]^T + bias)
// 128x128 tile, BK=32, 4 waves, m97 structure.
// MODE 1: out bf16, +bias, gelu          (FFN1)
// MODE 2: out f32, +bias, +Res f32       (O-proj / FFN2)
// MODE 3: out bf16, (acc+bias)*scale     (QKV; Q uses scale=0.125)
// ---------------------------------------------------------------------------
template <int MODE>
__global__ __launch_bounds__(256) void gemm_bf16(
    const unsigned short* __restrict__ A, const unsigned short* __restrict__ Bt,
    const float* __restrict__ bias, const float* __restrict__ Res,
    void* __restrict__ Cout, int M, int N, int K, float scale) {
  __shared__ unsigned short Abuf[128 * 32];
  __shared__ unsigned short Bbuf[128 * 32];
  const int tid = threadIdx.x;
  const int lane = tid & 63, w = tid >> 6;
  const int wm = w >> 1, wn = w & 1;
  const int m0 = blockIdx.y * 128, n0 = blockIdx.x * 128;

  f32x4 zero = {0.f, 0.f, 0.f, 0.f};
  f32x4 acc[4][4];
#pragma unroll
  for (int i = 0; i < 4; ++i)
#pragma unroll
    for (int j = 0; j < 4; ++j) acc[i][j] = zero;

  const int s0 = w * 64 + lane, s1 = 256 + w * 64 + lane;
  const int r0s = s0 >> 2, c0s = s0 & 3;
  const int r1s = s1 >> 2, c1s = s1 & 3;
  const unsigned short* gA0 = A + (size_t)(m0 + r0s) * K + c0s * 8;
  const unsigned short* gA1 = A + (size_t)(m0 + r1s) * K + c1s * 8;
  const unsigned short* gB0 = Bt + (size_t)(n0 + r0s) * K + c0s * 8;
  const unsigned short* gB1 = Bt + (size_t)(n0 + r1s) * K + c1s * 8;
  unsigned short* lA0 = Abuf + (w * 64) * 8;
  unsigned short* lA1 = Abuf + (256 + w * 64) * 8;
  unsigned short* lB0 = Bbuf + (w * 64) * 8;
  unsigned short* lB1 = Bbuf + (256 + w * 64) * 8;

  const int frow = lane & 15, kgrp = lane >> 4;
  int aoff[4], boff[4];
#pragma unroll
  for (int i = 0; i < 4; ++i) {
    aoff[i] = (wm * 64 + i * 16 + frow) * 32 + kgrp * 8;
    boff[i] = (wn * 64 + i * 16 + frow) * 32 + kgrp * 8;
  }

  const int nk = K >> 5;
  for (int kt = 0; kt < nk; ++kt) {
    __syncthreads();
    ASYNC_COPY16(gA0, lA0);
    ASYNC_COPY16(gA1, lA1);
    ASYNC_COPY16(gB0, lB0);
    ASYNC_COPY16(gB1, lB1);
    gA0 += 32; gA1 += 32; gB0 += 32; gB1 += 32;
    __syncthreads();
    bf16x8 av[4], bv[4];
#pragma unroll
    for (int i = 0; i < 4; ++i) av[i] = *(const bf16x8*)(Abuf + aoff[i]);
#pragma unroll
    for (int j = 0; j < 4; ++j) bv[j] = *(const bf16x8*)(Bbuf + boff[j]);
#pragma unroll
    for (int i = 0; i < 4; ++i)
#pragma unroll
      for (int j = 0; j < 4; ++j)
        acc[i][j] = MFMA_BF16(av[i], bv[j], acc[i][j]);
  }

#pragma unroll
  for (int i = 0; i < 4; ++i) {
#pragma unroll
    for (int j = 0; j < 4; ++j) {
      int grb = m0 + wm * 64 + i * 16 + (lane >> 4) * 4;
      int gc = n0 + wn * 64 + j * 16 + (lane & 15);
      float bsv = bias[gc];
#pragma unroll
      for (int r = 0; r < 4; ++r) {
        int gr = grb + r;
        float v = acc[i][j][r] + bsv;
        if (MODE == 1) {
          float x = v;
          float th = tanhf(0.7978845608028654f * (x + 0.044715f * x * x * x));
          v = 0.5f * x * (1.f + th);
        }
        if (MODE == 3) v *= scale;
        if (MODE == 2) v += Res[(size_t)gr * N + gc];
        if (MODE == 1 || MODE == 3)
          ((unsigned short*)Cout)[(size_t)gr * N + gc] = f2bf_bits(v);
        else
          ((float*)Cout)[(size_t)gr * N + gc] = v;
      }
    }
  }
}

// ---------------------------------------------------------------------------
// V transpose per (b,h): Vbf[B*S][768] -> Vt[(b*12+h)*64 + d][4096] bf16
// grid (64 keyblocks, 12, 2), 256 threads.
// ---------------------------------------------------------------------------
__global__ __launch_bounds__(256) void vtrans_kernel(
    const unsigned short* __restrict__ Vbf, unsigned short* __restrict__ Vt) {
  int kb = blockIdx.x, h = blockIdx.y, b = blockIdx.z;
  int k0 = kb * 64;
  const size_t bs = (size_t)b * S_LEN;
  const size_t bh = (size_t)(b * NHEAD + h);
  __shared__ unsigned short tile[64][72];
  int tid = threadIdx.x;
#pragma unroll
  for (int p = 0; p < 2; ++p) {
    int idx = p * 256 + tid;
    int key = idx >> 3, ch = idx & 7;
    bf16x8 v = *(const bf16x8*)(Vbf + (bs + k0 + key) * D_MODEL + h * DH + ch * 8);
    *(bf16x8*)&tile[key][ch * 8] = v;
  }
  __syncthreads();
#pragma unroll
  for (int p = 0; p < 2; ++p) {
    int idx = p * 256 + tid;
    int d = idx >> 3, kc = idx & 7;
    unsigned int w0 = tile[kc * 8 + 0][d] | ((unsigned int)tile[kc * 8 + 1][d] << 16);
    unsigned int w1 = tile[kc * 8 + 2][d] | ((unsigned int)tile[kc * 8 + 3][d] << 16);
    unsigned int w2 = tile[kc * 8 + 4][d] | ((unsigned int)tile[kc * 8 + 5][d] << 16);
    unsigned int w3 = tile[kc * 8 + 6][d] | ((unsigned int)tile[kc * 8 + 7][d] << 16);
    uint4 out = make_uint4(w0, w1, w2, w3);
    *(uint4*)(Vt + (bh * 64 + d) * S_LEN + k0 + kc * 8) = out;
  }
}

// ---------------------------------------------------------------------------
// MFMA band attention. grid (nc=16, H=12, B=2), 512 threads = 8 waves.
// Wave wq owns 32 query rows. Swapped QK^T (S^T = K·Q^T) so each lane owns
// one query column; P moved to PV A-fragments in-register via cvt_pk+shfl.
// Q is PRESCALED by 1/8 in the QKV GEMM. Online softmax seeded by global key.
// ---------------------------------------------------------------------------
__global__ __launch_bounds__(512) void band_attn_kernel(
    const unsigned short* __restrict__ Qg, const unsigned short* __restrict__ Kgb,
    const unsigned short* __restrict__ Vgb, const unsigned short* __restrict__ Vt,
    const int* __restrict__ att, unsigned short* __restrict__ Aout) {
  const int c = blockIdx.x, h = blockIdx.y, b = blockIdx.z;
  const int tid = threadIdx.x;
  const int lane = tid & 63, wq = tid >> 6;
  const int g = lane >> 4, cl = lane & 15;
  const size_t bs = (size_t)b * S_LEN;
  const size_t bh = (size_t)(b * NHEAD + h);

  __shared__ unsigned short Klds[64 * 64];   // [key][d], chunk-XOR swizzled
  __shared__ unsigned short Vlds[64 * 64];   // [d][key], chunk-XOR swizzled
  __shared__ float kmask[64];

  // Q fragments: q = c*256 + wq*32 + qt*16 + cl, d = ks*32 + g*8 .. +8
  bf16x8 qf[2][2];
#pragma unroll
  for (int qt = 0; qt < 2; ++qt)
#pragma unroll
    for (int ks = 0; ks < 2; ++ks)
      qf[qt][ks] = *(const bf16x8*)(Qg + (bs + c * 256 + wq * 32 + qt * 16 + cl) * D_MODEL +
                                    h * DH + ks * 32 + g * 8);

  // global key (pos 0) seeds online softmax
  float mrun[2], lrun[2];
  f32x4 oacc[2][4];
#pragma unroll
  for (int qt = 0; qt < 2; ++qt) {
    float sg = 0.f;
#pragma unroll
    for (int ks = 0; ks < 2; ++ks) {
      bf16x8 k0 = *(const bf16x8*)(Kgb + bs * D_MODEL + h * DH + ks * 32 + g * 8);
#pragma unroll
      for (int j = 0; j < 8; ++j) sg += (float)qf[qt][ks][j] * (float)k0[j];
    }
    sg += __shfl_xor(sg, 16, 64);
    sg += __shfl_xor(sg, 32, 64);
    mrun[qt] = sg;
    lrun[qt] = 1.f;
  }
#pragma unroll
  for (int dt = 0; dt < 4; ++dt) {
    float v0d = bf2f(Vgb[bs * D_MODEL + h * DH + dt * 16 + cl]);
    f32x4 vv = {v0d, v0d, v0d, v0d};
    oacc[0][dt] = vv;
    oacc[1][dt] = vv;
  }

  const int jlo = wq * 32, jhi = wq * 32 + 543;   // rel in [0,512] inclusive

  for (int t = 0; t < 12; ++t) {
    int kabs0 = c * 256 - 256 + t * 64;
    if (kabs0 < 0 || kabs0 >= S_LEN) continue;    // uniform skip
    __syncthreads();
    {
      int key = tid >> 3, ch = tid & 7;           // key doubles as d for Vt
      bf16x8 kv = *(const bf16x8*)(Kgb + (bs + kabs0 + key) * D_MODEL + h * DH + ch * 8);
      *(bf16x8*)(Klds + key * 64 + ((ch ^ (key & 7)) * 8)) = kv;
      bf16x8 vv = *(const bf16x8*)(Vt + (bh * 64 + key) * S_LEN + kabs0 + ch * 8);
      *(bf16x8*)(Vlds + key * 64 + ((ch ^ (key & 7)) * 8)) = vv;
      if (tid < 64) {
        int ka = kabs0 + tid;
        kmask[tid] = (ka >= 1 && att[b * S_LEN + ka] > 0) ? 0.f : -1e9f;
      }
    }
    __syncthreads();
    if (t * 64 + 63 < jlo || t * 64 > jhi) continue;  // per-wave skip (no barriers below)

    // QK^T: accs[kt][qt] = S^T tile, key = kt*16 + g*4 + r, q = qt*16 + cl
    f32x4 accs[4][2];
#pragma unroll
    for (int kt = 0; kt < 4; ++kt) {
      accs[kt][0] = (f32x4){0.f, 0.f, 0.f, 0.f};
      accs[kt][1] = (f32x4){0.f, 0.f, 0.f, 0.f};
    }
#pragma unroll
    for (int ks = 0; ks < 2; ++ks) {
      bf16x8 kf[4];
#pragma unroll
      for (int kt = 0; kt < 4; ++kt) {
        int key = kt * 16 + cl;
        kf[kt] = *(const bf16x8*)(Klds + key * 64 + (((ks * 4 + g) ^ (key & 7)) * 8));
      }
#pragma unroll
      for (int kt = 0; kt < 4; ++kt) {
        accs[kt][0] = MFMA_BF16(kf[kt], qf[0][ks], accs[kt][0]);
        accs[kt][1] = MFMA_BF16(kf[kt], qf[1][ks], accs[kt][1]);
      }
    }

#pragma unroll
    for (int qt = 0; qt < 2; ++qt) {
      int iq = wq * 32 + qt * 16 + cl;
      int relbase = t * 64 - iq;
      float pvv[4][4];
      float tmax = -1e30f;
#pragma unroll
      for (int kt = 0; kt < 4; ++kt)
#pragma unroll
        for (int r = 0; r < 4; ++r) {
          int key = kt * 16 + g * 4 + r;
          int rel = relbase + key;
          float x = accs[kt][qt][r] + kmask[key];
          x = (rel >= 0 && rel <= 512) ? x : -1e9f;
          pvv[kt][r] = x;
          tmax = fmaxf(tmax, x);
        }
      tmax = fmaxf(tmax, __shfl_xor(tmax, 16, 64));
      tmax = fmaxf(tmax, __shfl_xor(tmax, 32, 64));
      float mnew = fmaxf(mrun[qt], tmax);
      float scale = __expf(mrun[qt] - mnew);
      mrun[qt] = mnew;
      float psum = 0.f;
#pragma unroll
      for (int kt = 0; kt < 4; ++kt)
#pragma unroll
        for (int r = 0; r < 4; ++r) {
          float p = __expf(pvv[kt][r] - mnew);
          pvv[kt][r] = p;
          psum += p;
        }
      psum += __shfl_xor(psum, 16, 64);
      psum += __shfl_xor(psum, 32, 64);
      lrun[qt] = lrun[qt] * scale + psum;
      // rescale O rows (row q = g*4 + r within qt tile)
      float scr[4];
#pragma unroll
      for (int r = 0; r < 4; ++r) scr[r] = __shfl(scale, g * 4 + r, 64);
#pragma unroll
      for (int dt = 0; dt < 4; ++dt) {
        oacc[qt][dt][0] *= scr[0];
        oacc[qt][dt][1] *= scr[1];
        oacc[qt][dt][2] *= scr[2];
        oacc[qt][dt][3] *= scr[3];
      }
      // in-register P -> A-fragment exchange (cvt_pk + 8 shfl per ksub)
#pragma unroll
      for (int ks = 0; ks < 2; ++ks) {
        unsigned int E0D0 = cvtpk_bf16(pvv[ks * 2][0], pvv[ks * 2][1]);
        unsigned int E0D1 = cvtpk_bf16(pvv[ks * 2][2], pvv[ks * 2][3]);
        unsigned int E1D0 = cvtpk_bf16(pvv[ks * 2 + 1][0], pvv[ks * 2 + 1][1]);
        unsigned int E1D1 = cvtpk_bf16(pvv[ks * 2 + 1][2], pvv[ks * 2 + 1][3]);
        int src0 = ((lane >> 4) & 1) * 32 + cl;
        int src1 = src0 + 16;
        unsigned int a0 = (unsigned int)__shfl((int)E0D0, src0, 64);
        unsigned int a1 = (unsigned int)__shfl((int)E0D1, src0, 64);
        unsigned int a2 = (unsigned int)__shfl((int)E0D0, src1, 64);
        unsigned int a3 = (unsigned int)__shfl((int)E0D1, src1, 64);
        unsigned int b0 = (unsigned int)__shfl((int)E1D0, src0, 64);
        unsigned int b1 = (unsigned int)__shfl((int)E1D1, src0, 64);
        unsigned int b2 = (unsigned int)__shfl((int)E1D0, src1, 64);
        unsigned int b3 = (unsigned int)__shfl((int)E1D1, src1, 64);
        bool hi = lane >= 32;
        union { unsigned int u[4]; bf16x8 v; } af;
        af.u[0] = hi ? b0 : a0;
        af.u[1] = hi ? b1 : a1;
        af.u[2] = hi ? b2 : a2;
        af.u[3] = hi ? b3 : a3;
#pragma unroll
        for (int dt = 0; dt < 4; ++dt) {
          int d = dt * 16 + cl;
          bf16x8 vf = *(const bf16x8*)(Vlds + d * 64 + (((ks * 4 + g) ^ (d & 7)) * 8));
          oacc[qt][dt] = MFMA_BF16(af.v, vf, oacc[qt][dt]);
        }
      }
    }
  }

  // write out: row q = g*4 + r + qt*16, col d = dt*16 + cl
#pragma unroll
  for (int qt = 0; qt < 2; ++qt) {
    float lr[4];
#pragma unroll
    for (int r = 0; r < 4; ++r) lr[r] = 1.f / __shfl(lrun[qt], g * 4 + r, 64);
#pragma unroll
    for (int dt = 0; dt < 4; ++dt)
#pragma unroll
      for (int r = 0; r < 4; ++r) {
        int row = c * 256 + wq * 32 + qt * 16 + g * 4 + r;
        Aout[(bs + row) * D_MODEL + h * DH + dt * 16 + cl] =
            f2bf_bits(oacc[qt][dt][r] * lr[r]);
      }
  }
}

// ---------------------------------------------------------------------------
// global row 0 attends to all S keys (bf16 inputs; Q prescaled).
// ---------------------------------------------------------------------------
__global__ __launch_bounds__(256) void global_attn_kernel(
    const unsigned short* __restrict__ Q, const unsigned short* __restrict__ K,
    const unsigned short* __restrict__ V, const int* __restrict__ att,
    unsigned short* __restrict__ Aout) {
  int h = blockIdx.x, b = blockIdx.y;
  int t = threadIdx.x;
  __shared__ float sc[S_LEN];
  __shared__ float q0[64];
  __shared__ float red[4];
  __shared__ float part[4][64];
  const size_t bs = (size_t)b * S_LEN;
  if (t < 64) q0[t] = bf2f(Q[bs * D_MODEL + h * DH + t]);
  __syncthreads();
  float lmax = -1e30f;
  for (int s = t; s < S_LEN; s += 256) {
    const unsigned short* kp = K + (bs + s) * D_MODEL + h * DH;
    float acc = 0.f;
#pragma unroll
    for (int cc = 0; cc < 8; ++cc) {
      uint4 u = *(const uint4*)(kp + cc * 8);
      const unsigned int* uu = (const unsigned int*)&u;
#pragma unroll
      for (int w2 = 0; w2 < 4; ++w2) {
        unsigned int x = uu[w2];
        acc += q0[cc * 8 + w2 * 2] * __uint_as_float(x << 16);
        acc += q0[cc * 8 + w2 * 2 + 1] * __uint_as_float(x & 0xffff0000u);
      }
    }
    acc = (att[b * S_LEN + s] > 0) ? acc : -1e9f;
    sc[s] = acc;
    lmax = fmaxf(lmax, acc);
  }
  float M = blk_max256(lmax, red);
  float lsum = 0.f;
  for (int s = t; s < S_LEN; s += 256) {
    float p = __expf(sc[s] - M);
    sc[s] = p;
    lsum += p;
  }
  float L = blk_sum256(lsum, red);
  int d = t & 63, chunk = t >> 6;
  float acc2 = 0.f;
  for (int s = chunk * 1024; s < (chunk + 1) * 1024; ++s)
    acc2 += sc[s] * bf2f(V[(bs + s) * D_MODEL + h * DH + d]);
  part[chunk][d] = acc2;
  __syncthreads();
  if (t < 64) {
    float v = (part[0][t] + part[1][t] + part[2][t] + part[3][t]) / L;
    Aout[bs * D_MODEL + h * DH + t] = f2bf_bits(v);
  }
}

// ---------------------------------------------------------------------------
// masked mean-pool, two stages
// ---------------------------------------------------------------------------
__global__ __launch_bounds__(256) void pool1_kernel(
    const float* __restrict__ X, const int* __restrict__ att,
    float* __restrict__ ppart) {
  int sb = blockIdx.x, b = blockIdx.y, t = threadIdx.x;
  float a0 = 0.f, a1 = 0.f, a2 = 0.f;
  for (int s = sb * 256; s < sb * 256 + 256; ++s) {
    float a = (float)att[b * S_LEN + s];
    const float* xp = X + ((size_t)b * S_LEN + s) * D_MODEL;
    a0 += xp[t] * a; a1 += xp[t + 256] * a; a2 += xp[t + 512] * a;
  }
  float* pp = ppart + ((size_t)b * 16 + sb) * D_MODEL;
  pp[t] = a0; pp[t + 256] = a1; pp[t + 512] = a2;
}

__global__ __launch_bounds__(256) void pool2_kernel(
    const float* __restrict__ ppart, const int* __restrict__ att,
    float* __restrict__ pooled) {
  int b = blockIdx.x, t = threadIdx.x;
  float a0 = 0.f, a1 = 0.f, a2 = 0.f;
  for (int sb = 0; sb < 16; ++sb) {
    const float* pp = ppart + ((size_t)b * 16 + sb) * D_MODEL;
    a0 += pp[t]; a1 += pp[t + 256]; a2 += pp[t + 512];
  }
  float cnt = 0.f;
  for (int s = 0; s < S_LEN; ++s) cnt += (float)att[b * S_LEN + s];
  cnt = fmaxf(cnt, 1e-9f);
  pooled[b * D_MODEL + t]       = a0 / cnt;
  pooled[b * D_MODEL + t + 256] = a1 / cnt;
  pooled[b * D_MODEL + t + 512] = a2 / cnt;
}

// ---------------------------------------------------------------------------
// head: h = relu(pooled @ Wh1 + bh1); out = sigmoid(h @ Wh2 + bh2) * 4
// ---------------------------------------------------------------------------
__global__ __launch_bounds__(256) void head_kernel(
    const float* __restrict__ pooled, const float* __restrict__ Wh1,
    const float* __restrict__ bh1, const float* __restrict__ Wh2,
    const float* __restrict__ bh2, float* __restrict__ out) {
  __shared__ float hbuf[2][256];
  int t = threadIdx.x;
  for (int b = 0; b < 2; ++b) {
    float acc = bh1[t];
    for (int d = 0; d < D_MODEL; ++d) acc += pooled[b * D_MODEL + d] * Wh1[d * 256 + t];
    hbuf[b][t] = fmaxf(acc, 0.f);
  }
  __syncthreads();
  if (t < 28) {
    int b = t / 14, j = t % 14;
    float acc = bh2[j];
    for (int i = 0; i < 256; ++i) acc += hbuf[b][i] * Wh2[i * 14 + j];
    out[t] = 4.f / (1.f + __expf(-acc));
  }
}

// ---------------------------------------------------------------------------
static void run_gemm_bf16(const unsigned short* A, const unsigned short* Bt,
                          const float* bias, const float* Res, void* C, int M,
                          int N, int K, int mode, float scale, hipStream_t st) {
  dim3 grid(N / 128, M / 128);
  if (mode == 1)
    gemm_bf16<1><<<grid, 256, 0, st>>>(A, Bt, bias, nullptr, C, M, N, K, 1.f);
  else if (mode == 2)
    gemm_bf16<2><<<grid, 256, 0, st>>>(A, Bt, bias, Res, C, M, N, K, 1.f);
  else
    gemm_bf16<3><<<grid, 256, 0, st>>>(A, Bt, bias, nullptr, C, M, N, K, scale);
}

extern "C" void kernel_launch(void* const* d_in, const int* in_sizes, int n_in,
                              void* d_out, int out_size, void* d_ws,
                              size_t ws_size, hipStream_t stream) {
  const int* ids    = (const int*)d_in[0];
  const int* att    = (const int*)d_in[1];
  const float* wemb = (const float*)d_in[2];
  const float* pemb = (const float*)d_in[3];
  const float* elng = (const float*)d_in[4];
  const float* elnb = (const float*)d_in[5];
  const float* Wq   = (const float*)d_in[6];
  const float* bq   = (const float*)d_in[7];
  const float* Wk   = (const float*)d_in[8];
  const float* bk   = (const float*)d_in[9];
  const float* Wv   = (const float*)d_in[10];
  const float* bv   = (const float*)d_in[11];
  const float* Wo   = (const float*)d_in[12];
  const float* bo   = (const float*)d_in[13];
  const float* ln1g = (const float*)d_in[14];
  const float* ln1b = (const float*)d_in[15];
  const float* Wf1  = (const float*)d_in[16];
  const float* bf1  = (const float*)d_in[17];
  const float* Wf2  = (const float*)d_in[18];
  const float* bf2  = (const float*)d_in[19];
  const float* ln2g = (const float*)d_in[20];
  const float* ln2b = (const float*)d_in[21];
  const float* Wh1  = (const float*)d_in[22];
  const float* bh1  = (const float*)d_in[23];
  const float* Wh2  = (const float*)d_in[24];
  const float* bh2  = (const float*)d_in[25];

  const int M = BATCH * S_LEN;  // 8192
  float* ws = (float*)d_ws;
  float* X  = ws;                                    // [0, 6291456)
  float* T  = ws + 6291456;                          // [6291456, 12582912)
  unsigned short* Qbf = (unsigned short*)(ws + 12582912);  // 6.29M bf16
  unsigned short* Kbf = (unsigned short*)(ws + 15728640);
  unsigned short* Vbf = (unsigned short*)(ws + 18874368);
  unsigned short* Vt  = (unsigned short*)(ws + 22020096);
  unsigned short* FFbf = Qbf;                        // overlays Qbf..Vt (FFN phase)
  unsigned short* Abbf = (unsigned short*)(ws + 25165824);
  unsigned short* Xbf  = (unsigned short*)(ws + 28311552);
  unsigned short* Wbf  = (unsigned short*)(ws + 31457280);  // 14.16M bf16
  float* pooled = ws + 38535168;
  float* ppart  = ws + 38536704;

  wconv_kernel<<<13824, 256, 0, stream>>>(Wq, Wk, Wv, Wo, Wf1, Wf2, Wbf);
  embed_ln_kernel<<<M, 256, 0, stream>>>(ids, wemb, pemb, elng, elnb, X, Xbf);

  for (int l = 0; l < NLAYER; ++l) {
    const unsigned short* wqt  = Wbf + (size_t)l * 7077888;
    const unsigned short* wkt  = wqt + 589824;
    const unsigned short* wvt  = wqt + 1179648;
    const unsigned short* wot  = wqt + 1769472;
    const unsigned short* wf1t = wqt + 2359296;
    const unsigned short* wf2t = wqt + 4718592;

    run_gemm_bf16(Xbf, wqt, bq + l * D_MODEL, nullptr, Qbf, M, 768, 768, 3, 0.125f, stream);
    run_gemm_bf16(Xbf, wkt, bk + l * D_MODEL, nullptr, Kbf, M, 768, 768, 3, 1.f, stream);
    run_gemm_bf16(Xbf, wvt, bv + l * D_MODEL, nullptr, Vbf, M, 768, 768, 3, 1.f, stream);

    vtrans_kernel<<<dim3(64, NHEAD, BATCH), 256, 0, stream>>>(Vbf, Vt);
    band_attn_kernel<<<dim3(16, NHEAD, BATCH), 512, 0, stream>>>(Qbf, Kbf, Vbf, Vt, att, Abbf);
    global_attn_kernel<<<dim3(NHEAD, BATCH), 256, 0, stream>>>(Qbf, Kbf, Vbf, att, Abbf);

    run_gemm_bf16(Abbf, wot, bo + l * D_MODEL, X, T, M, 768, 768, 2, 1.f, stream);
    ln_kernel<<<M, 256, 0, stream>>>(T, ln1g + l * D_MODEL, ln1b + l * D_MODEL, X, Xbf);

    run_gemm_bf16(Xbf, wf1t, bf1 + l * DFF, nullptr, FFbf, M, DFF, 768, 1, 1.f, stream);
    run_gemm_bf16(FFbf, wf2t, bf2 + l * D_MODEL, X, T, M, 768, DFF, 2, 1.f, stream);
    ln_kernel<<<M, 256, 0, stream>>>(T, ln2g + l * D_MODEL, ln2b + l * D_MODEL, X, Xbf);
  }

  pool1_kernel<<<dim3(16, BATCH), 256, 0, stream>>>(X, att, ppart);
  pool2_kernel<<<BATCH, 256, 0, stream>>>(ppart, att, pooled);
  head_kernel<<<1, 256, 0, stream>>>(pooled, Wh1, bh1, Wh2, bh2, (float*)d_out);
}

// Round 4
// 1040.909 us; speedup vs baseline: 4.4857x; 1.0611x over previous
//
#include <hip/hip_runtime.h>
#include <hip/hip_bf16.h>
#include <math.h>

#define S_LEN 4096
#define D_MODEL 768
#define NHEAD 12
#define DH 64
#define NLAYER 2
#define DFF 3072
#define BATCH 2
#define QSTR 2304   // fused QKV row stride

typedef __attribute__((ext_vector_type(8))) __bf16 bf16x8;
typedef __attribute__((ext_vector_type(4))) float f32x4;

// fp32 -> bf16 bits, round-to-nearest-even (finite inputs)
__device__ __forceinline__ unsigned short f2bf_bits(float f) {
  unsigned int u = __float_as_uint(f);
  unsigned int r = (u + 0x7fffu + ((u >> 16) & 1u)) >> 16;
  return (unsigned short)r;
}

__device__ __forceinline__ float bf2f(unsigned short u) {
  return __uint_as_float(((unsigned int)u) << 16);
}

// pack two f32 into one dword of two bf16 (RNE)
__device__ __forceinline__ unsigned int cvtpk_bf16(float lo, float hi) {
  unsigned int d;
  asm("v_cvt_pk_bf16_f32 %0, %1, %2" : "=v"(d) : "v"(lo), "v"(hi));
  return d;
}

#define ASYNC_COPY16(gsrc, ldst)                                       \
  __builtin_amdgcn_global_load_lds(                                    \
      (const __attribute__((address_space(1))) void*)(gsrc),           \
      (__attribute__((address_space(3))) void*)(ldst), 16, 0, 0)

#define MFMA_BF16(a, b, c) __builtin_amdgcn_mfma_f32_16x16x32_bf16(a, b, c, 0, 0, 0)

// ---------------------------------------------------------------------------
// block-wide reductions (256 threads = 4 waves of 64)
// ---------------------------------------------------------------------------
__device__ __forceinline__ float blk_sum256(float v, float* lds) {
#pragma unroll
  for (int off = 32; off > 0; off >>= 1) v += __shfl_down(v, off, 64);
  __syncthreads();
  if ((threadIdx.x & 63) == 0) lds[threadIdx.x >> 6] = v;
  __syncthreads();
  return lds[0] + lds[1] + lds[2] + lds[3];
}

__device__ __forceinline__ float blk_max256(float v, float* lds) {
#pragma unroll
  for (int off = 32; off > 0; off >>= 1) v = fmaxf(v, __shfl_down(v, off, 64));
  __syncthreads();
  if ((threadIdx.x & 63) == 0) lds[threadIdx.x >> 6] = v;
  __syncthreads();
  return fmaxf(fmaxf(lds[0], lds[1]), fmaxf(lds[2], lds[3]));
}

// ---------------------------------------------------------------------------
// weight transpose + fp32->bf16 convert: W[K][N] f32 -> Wt[N][K] bf16
// ---------------------------------------------------------------------------
__global__ __launch_bounds__(256) void wconv_kernel(
    const float* __restrict__ Wq, const float* __restrict__ Wk,
    const float* __restrict__ Wv, const float* __restrict__ Wo,
    const float* __restrict__ Wf1, const float* __restrict__ Wf2,
    unsigned short* __restrict__ Wbf) {
  int id = blockIdx.x;
  const float* src;
  unsigned short* dst;
  int K, N, t;
  if (id < 4608) {                       // Wq/Wk/Wv/Wo, 576 tiles each
    int m = id / 576;
    t = id % 576;
    int layer = m >> 2, which = m & 3;
    const float* s = (which == 0) ? Wq : (which == 1) ? Wk : (which == 2) ? Wv : Wo;
    src = s + (size_t)layer * 589824;
    dst = Wbf + (size_t)layer * 7077888 + (size_t)which * 589824;
    K = 768; N = 768;
  } else if (id < 9216) {                // Wf1 [768][3072]
    int j = id - 4608;
    int layer = j / 2304;
    t = j % 2304;
    src = Wf1 + (size_t)layer * 2359296;
    dst = Wbf + (size_t)layer * 7077888 + 2359296;
    K = 768; N = 3072;
  } else {                               // Wf2 [3072][768]
    int j = id - 9216;
    int layer = j / 2304;
    t = j % 2304;
    src = Wf2 + (size_t)layer * 2359296;
    dst = Wbf + (size_t)layer * 7077888 + 4718592;
    K = 3072; N = 768;
  }
  int tiles_n = N >> 5;
  int tk = t / tiles_n, tn = t % tiles_n;
  __shared__ float tile[32][33];
  int c = threadIdx.x & 31, r0 = threadIdx.x >> 5;
#pragma unroll
  for (int p = 0; p < 4; ++p) {
    int r = r0 + p * 8;
    tile[r][c] = src[(size_t)(tk * 32 + r) * N + tn * 32 + c];
  }
  __syncthreads();
#pragma unroll
  for (int p = 0; p < 4; ++p) {
    int r = r0 + p * 8;  // local n index
    dst[(size_t)(tn * 32 + r) * K + tk * 32 + c] = f2bf_bits(tile[c][r]);
  }
}

// ---------------------------------------------------------------------------
// embedding gather + LayerNorm; writes fp32 X and bf16 Xb
// ---------------------------------------------------------------------------
__global__ __launch_bounds__(256) void embed_ln_kernel(
    const int* __restrict__ ids, const float* __restrict__ wemb,
    const float* __restrict__ pemb, const float* __restrict__ g,
    const float* __restrict__ b, float* __restrict__ X,
    unsigned short* __restrict__ Xb) {
  int row = blockIdx.x;
  int s = row % S_LEN;
  int id = ids[row];
  const float* we = wemb + (size_t)id * D_MODEL;
  const float* pe = pemb + (size_t)s * D_MODEL;
  int t = threadIdx.x;
  __shared__ float lds[4];
  float v0 = we[t] + pe[t];
  float v1 = we[t + 256] + pe[t + 256];
  float v2 = we[t + 512] + pe[t + 512];
  float mean = blk_sum256(v0 + v1 + v2, lds) * (1.f / 768.f);
  float d0 = v0 - mean, d1 = v1 - mean, d2 = v2 - mean;
  float var = blk_sum256(d0 * d0 + d1 * d1 + d2 * d2, lds) * (1.f / 768.f);
  float rs = rsqrtf(var + 1e-5f);
  float o0 = d0 * rs * g[t] + b[t];
  float o1 = d1 * rs * g[t + 256] + b[t + 256];
  float o2 = d2 * rs * g[t + 512] + b[t + 512];
  float* xp = X + (size_t)row * D_MODEL;
  xp[t] = o0; xp[t + 256] = o1; xp[t + 512] = o2;
  unsigned short* xb = Xb + (size_t)row * D_MODEL;
  xb[t] = f2bf_bits(o0); xb[t + 256] = f2bf_bits(o1); xb[t + 512] = f2bf_bits(o2);
}

// ---------------------------------------------------------------------------
// LayerNorm: X = LN(T) * g + b ; writes fp32 X and bf16 Xb
// ---------------------------------------------------------------------------
__global__ __launch_bounds__(256) void ln_kernel(
    const float* __restrict__ T, const float* __restrict__ g,
    const float* __restrict__ b, float* __restrict__ X,
    unsigned short* __restrict__ Xb) {
  int row = blockIdx.x;
  const float* tp = T + (size_t)row * D_MODEL;
  int t = threadIdx.x;
  __shared__ float lds[4];
  float v0 = tp[t], v1 = tp[t + 256], v2 = tp[t + 512];
  float mean = blk_sum256(v0 + v1 + v2, lds) * (1.f / 768.f);
  float d0 = v0 - mean, d1 = v1 - mean, d2 = v2 - mean;
  float var = blk_sum256(d0 * d0 + d1 * d1 + d2 * d2, lds) * (1.f / 768.f);
  float rs = rsqrtf(var + 1e-5f);
  float o0 = d0 * rs * g[t] + b[t];
  float o1 = d1 * rs * g[t + 256] + b[t + 256];
  float o2 = d2 * rs * g[t + 512] + b[t + 512];
  float* xp = X + (size_t)row * D_MODEL;
  xp[t] = o0; xp[t + 256] = o1; xp[t + 512] = o2;
  unsigned short* xb = Xb + (size_t)row * D_MODEL;
  xb[t] = f2bf_bits(o0); xb[t + 256] = f2bf_bits(o1); xb[t + 512] = f2bf_bits(o2);
}

// ---------------------------------------------------------------------------
// bf16 MFMA GEMM: C = epilogue(A[MxK] @ Bt[NxK]^T + bias)
// 128x128 tile, BK=32, 4 waves. Depth-1 prefetch (double-buffered LDS),
// chunk-XOR LDS swizzle (source-permuted, rule-21 both-sides), XCD block
// swizzle (requires nwg % 8 == 0).
// MODE 1: out bf16, +bias0, gelu               (FFN1)
// MODE 2: out f32, +bias0, +Res f32            (O-proj / FFN2)
// MODE 4: out bf16 stride N, bias from 3 arrays, cols<768 scaled 1/8 (QKV)
// ---------------------------------------------------------------------------
template <int MODE>
__global__ __launch_bounds__(256) void gemm_bf16(
    const unsigned short* __restrict__ A, const unsigned short* __restrict__ Bt,
    const float* __restrict__ bias0, const float* __restrict__ bias1,
    const float* __restrict__ bias2, const float* __restrict__ Res,
    void* __restrict__ Cout, int M, int N, int K) {
  __shared__ unsigned short Abuf[2][128 * 32];
  __shared__ unsigned short Bbuf[2][128 * 32];
  const int tid = threadIdx.x;
  const int lane = tid & 63, w = tid >> 6;
  const int wm = w >> 1, wn = w & 1;

  // XCD-aware bijective block swizzle (nwg % 8 == 0 for all our grids)
  const int nbx = gridDim.x;
  const int nwg = nbx * gridDim.y;
  const int orig = blockIdx.y * nbx + blockIdx.x;
  const int wgid = (orig & 7) * (nwg >> 3) + (orig >> 3);
  const int m0 = (wgid / nbx) * 128, n0 = (wgid % nbx) * 128;

  f32x4 acc[4][4];
#pragma unroll
  for (int i = 0; i < 4; ++i)
#pragma unroll
    for (int j = 0; j < 4; ++j) acc[i][j] = (f32x4){0.f, 0.f, 0.f, 0.f};

  // staging: slot s covers row r = s>>2, 16B-chunk c = s&3.
  // SOURCE chunk is permuted: c_src = c ^ (r&3)  (LDS dest stays linear).
  const int s0 = w * 64 + lane, s1 = s0 + 256;
  const int r0 = s0 >> 2, c0 = (s0 & 3) ^ (r0 & 3);
  const int r1 = s1 >> 2, c1 = (s1 & 3) ^ (r1 & 3);
  const unsigned short* gA0 = A + (size_t)(m0 + r0) * K + c0 * 8;
  const unsigned short* gA1 = A + (size_t)(m0 + r1) * K + c1 * 8;
  const unsigned short* gB0 = Bt + (size_t)(n0 + r0) * K + c0 * 8;
  const unsigned short* gB1 = Bt + (size_t)(n0 + r1) * K + c1 * 8;
  const int dA0 = (w * 64) * 8, dA1 = (256 + w * 64) * 8;  // wave-uniform elems

  // fragment read offsets with matching XOR: chunk = kgrp ^ (row&3)
  const int frow = lane & 15, kgrp = lane >> 4;
  int aoff[4], boff[4];
#pragma unroll
  for (int i = 0; i < 4; ++i) {
    int ra = wm * 64 + i * 16 + frow;
    int rb = wn * 64 + i * 16 + frow;
    aoff[i] = ra * 32 + ((kgrp ^ (ra & 3)) * 8);
    boff[i] = rb * 32 + ((kgrp ^ (rb & 3)) * 8);
  }

#define STAGE(bsel)                                                       \
  {                                                                       \
    ASYNC_COPY16(gA0, &Abuf[bsel][dA0]);                                  \
    ASYNC_COPY16(gA1, &Abuf[bsel][dA1]);                                  \
    ASYNC_COPY16(gB0, &Bbuf[bsel][dA0]);                                  \
    ASYNC_COPY16(gB1, &Bbuf[bsel][dA1]);                                  \
    gA0 += 32; gA1 += 32; gB0 += 32; gB1 += 32;                           \
  }

  const int nk = K >> 5;
  STAGE(0);
  __syncthreads();
  int cur = 0;
  for (int kt = 0; kt < nk; ++kt) {
    if (kt + 1 < nk) STAGE(cur ^ 1);          // prefetch next tile
    bf16x8 av[4], bv[4];
#pragma unroll
    for (int i = 0; i < 4; ++i) av[i] = *(const bf16x8*)(&Abuf[cur][aoff[i]]);
#pragma unroll
    for (int j = 0; j < 4; ++j) bv[j] = *(const bf16x8*)(&Bbuf[cur][boff[j]]);
#pragma unroll
    for (int i = 0; i < 4; ++i)
#pragma unroll
      for (int j = 0; j < 4; ++j)
        acc[i][j] = MFMA_BF16(av[i], bv[j], acc[i][j]);
    __syncthreads();                           // drains vmcnt+lgkm, barrier
    cur ^= 1;
  }
#undef STAGE

  // epilogue: C/D layout col = lane&15, row = (lane>>4)*4 + reg
#pragma unroll
  for (int i = 0; i < 4; ++i) {
#pragma unroll
    for (int j = 0; j < 4; ++j) {
      int grb = m0 + wm * 64 + i * 16 + (lane >> 4) * 4;
      int gc = n0 + wn * 64 + j * 16 + (lane & 15);
      float bsv;
      if (MODE == 4)
        bsv = (gc < 768) ? bias0[gc] : (gc < 1536) ? bias1[gc - 768] : bias2[gc - 1536];
      else
        bsv = bias0[gc];
#pragma unroll
      for (int r = 0; r < 4; ++r) {
        int gr = grb + r;
        float v = acc[i][j][r] + bsv;
        if (MODE == 1) {
          float x = v;
          float th = tanhf(0.7978845608028654f * (x + 0.044715f * x * x * x));
          v = 0.5f * x * (1.f + th);
        }
        if (MODE == 4 && gc < 768) v *= 0.125f;
        if (MODE == 2) v += Res[(size_t)gr * N + gc];
        if (MODE == 1 || MODE == 4)
          ((unsigned short*)Cout)[(size_t)gr * N + gc] = f2bf_bits(v);
        else
          ((float*)Cout)[(size_t)gr * N + gc] = v;
      }
    }
  }
}

// ---------------------------------------------------------------------------
// V transpose per (b,h): QKV V-cols -> Vt[(b*12+h)*64 + d][4096] bf16
// ---------------------------------------------------------------------------
__global__ __launch_bounds__(256) void vtrans_kernel(
    const unsigned short* __restrict__ Vsrc, unsigned short* __restrict__ Vt) {
  int kb = blockIdx.x, h = blockIdx.y, b = blockIdx.z;
  int k0 = kb * 64;
  const size_t bs = (size_t)b * S_LEN;
  const size_t bh = (size_t)(b * NHEAD + h);
  __shared__ unsigned short tile[64][72];
  int tid = threadIdx.x;
#pragma unroll
  for (int p = 0; p < 2; ++p) {
    int idx = p * 256 + tid;
    int key = idx >> 3, ch = idx & 7;
    bf16x8 v = *(const bf16x8*)(Vsrc + (bs + k0 + key) * QSTR + h * DH + ch * 8);
    *(bf16x8*)&tile[key][ch * 8] = v;
  }
  __syncthreads();
#pragma unroll
  for (int p = 0; p < 2; ++p) {
    int idx = p * 256 + tid;
    int d = idx >> 3, kc = idx & 7;
    unsigned int w0 = tile[kc * 8 + 0][d] | ((unsigned int)tile[kc * 8 + 1][d] << 16);
    unsigned int w1 = tile[kc * 8 + 2][d] | ((unsigned int)tile[kc * 8 + 3][d] << 16);
    unsigned int w2 = tile[kc * 8 + 4][d] | ((unsigned int)tile[kc * 8 + 5][d] << 16);
    unsigned int w3 = tile[kc * 8 + 6][d] | ((unsigned int)tile[kc * 8 + 7][d] << 16);
    uint4 out = make_uint4(w0, w1, w2, w3);
    *(uint4*)(Vt + (bh * 64 + d) * S_LEN + k0 + kc * 8) = out;
  }
}

// ---------------------------------------------------------------------------
// MFMA band attention. grid (nc=16, H=12, B=2), 512 threads = 8 waves.
// Q/K/V read from fused QKV buffer (row stride QSTR); Q prescaled by 1/8.
// ---------------------------------------------------------------------------
__global__ __launch_bounds__(512) void band_attn_kernel(
    const unsigned short* __restrict__ Qg, const unsigned short* __restrict__ Kgb,
    const unsigned short* __restrict__ Vgb, const unsigned short* __restrict__ Vt,
    const int* __restrict__ att, unsigned short* __restrict__ Aout) {
  const int c = blockIdx.x, h = blockIdx.y, b = blockIdx.z;
  const int tid = threadIdx.x;
  const int lane = tid & 63, wq = tid >> 6;
  const int g = lane >> 4, cl = lane & 15;
  const size_t bs = (size_t)b * S_LEN;
  const size_t bh = (size_t)(b * NHEAD + h);

  __shared__ unsigned short Klds[64 * 64];   // [key][d], chunk-XOR swizzled
  __shared__ unsigned short Vlds[64 * 64];   // [d][key], chunk-XOR swizzled
  __shared__ float kmask[64];

  bf16x8 qf[2][2];
#pragma unroll
  for (int qt = 0; qt < 2; ++qt)
#pragma unroll
    for (int ks = 0; ks < 2; ++ks)
      qf[qt][ks] = *(const bf16x8*)(Qg + (bs + c * 256 + wq * 32 + qt * 16 + cl) * QSTR +
                                    h * DH + ks * 32 + g * 8);

  float mrun[2], lrun[2];
  f32x4 oacc[2][4];
#pragma unroll
  for (int qt = 0; qt < 2; ++qt) {
    float sg = 0.f;
#pragma unroll
    for (int ks = 0; ks < 2; ++ks) {
      bf16x8 k0 = *(const bf16x8*)(Kgb + bs * QSTR + h * DH + ks * 32 + g * 8);
#pragma unroll
      for (int j = 0; j < 8; ++j) sg += (float)qf[qt][ks][j] * (float)k0[j];
    }
    sg += __shfl_xor(sg, 16, 64);
    sg += __shfl_xor(sg, 32, 64);
    mrun[qt] = sg;
    lrun[qt] = 1.f;
  }
#pragma unroll
  for (int dt = 0; dt < 4; ++dt) {
    float v0d = bf2f(Vgb[bs * QSTR + h * DH + dt * 16 + cl]);
    f32x4 vv = {v0d, v0d, v0d, v0d};
    oacc[0][dt] = vv;
    oacc[1][dt] = vv;
  }

  const int jlo = wq * 32, jhi = wq * 32 + 543;

  for (int t = 0; t < 12; ++t) {
    int kabs0 = c * 256 - 256 + t * 64;
    if (kabs0 < 0 || kabs0 >= S_LEN) continue;
    __syncthreads();
    {
      int key = tid >> 3, ch = tid & 7;
      bf16x8 kv = *(const bf16x8*)(Kgb + (bs + kabs0 + key) * QSTR + h * DH + ch * 8);
      *(bf16x8*)(Klds + key * 64 + ((ch ^ (key & 7)) * 8)) = kv;
      bf16x8 vv = *(const bf16x8*)(Vt + (bh * 64 + key) * S_LEN + kabs0 + ch * 8);
      *(bf16x8*)(Vlds + key * 64 + ((ch ^ (key & 7)) * 8)) = vv;
      if (tid < 64) {
        int ka = kabs0 + tid;
        kmask[tid] = (ka >= 1 && att[b * S_LEN + ka] > 0) ? 0.f : -1e9f;
      }
    }
    __syncthreads();
    if (t * 64 + 63 < jlo || t * 64 > jhi) continue;

    f32x4 accs[4][2];
#pragma unroll
    for (int kt = 0; kt < 4; ++kt) {
      accs[kt][0] = (f32x4){0.f, 0.f, 0.f, 0.f};
      accs[kt][1] = (f32x4){0.f, 0.f, 0.f, 0.f};
    }
#pragma unroll
    for (int ks = 0; ks < 2; ++ks) {
      bf16x8 kf[4];
#pragma unroll
      for (int kt = 0; kt < 4; ++kt) {
        int key = kt * 16 + cl;
        kf[kt] = *(const bf16x8*)(Klds + key * 64 + (((ks * 4 + g) ^ (key & 7)) * 8));
      }
#pragma unroll
      for (int kt = 0; kt < 4; ++kt) {
        accs[kt][0] = MFMA_BF16(kf[kt], qf[0][ks], accs[kt][0]);
        accs[kt][1] = MFMA_BF16(kf[kt], qf[1][ks], accs[kt][1]);
      }
    }

#pragma unroll
    for (int qt = 0; qt < 2; ++qt) {
      int iq = wq * 32 + qt * 16 + cl;
      int relbase = t * 64 - iq;
      float pvv[4][4];
      float tmax = -1e30f;
#pragma unroll
      for (int kt = 0; kt < 4; ++kt)
#pragma unroll
        for (int r = 0; r < 4; ++r) {
          int key = kt * 16 + g * 4 + r;
          int rel = relbase + key;
          float x = accs[kt][qt][r] + kmask[key];
          x = (rel >= 0 && rel <= 512) ? x : -1e9f;
          pvv[kt][r] = x;
          tmax = fmaxf(tmax, x);
        }
      tmax = fmaxf(tmax, __shfl_xor(tmax, 16, 64));
      tmax = fmaxf(tmax, __shfl_xor(tmax, 32, 64));
      float mnew = fmaxf(mrun[qt], tmax);
      float scale = __expf(mrun[qt] - mnew);
      mrun[qt] = mnew;
      float psum = 0.f;
#pragma unroll
      for (int kt = 0; kt < 4; ++kt)
#pragma unroll
        for (int r = 0; r < 4; ++r) {
          float p = __expf(pvv[kt][r] - mnew);
          pvv[kt][r] = p;
          psum += p;
        }
      psum += __shfl_xor(psum, 16, 64);
      psum += __shfl_xor(psum, 32, 64);
      lrun[qt] = lrun[qt] * scale + psum;
      float scr[4];
#pragma unroll
      for (int r = 0; r < 4; ++r) scr[r] = __shfl(scale, g * 4 + r, 64);
#pragma unroll
      for (int dt = 0; dt < 4; ++dt) {
        oacc[qt][dt][0] *= scr[0];
        oacc[qt][dt][1] *= scr[1];
        oacc[qt][dt][2] *= scr[2];
        oacc[qt][dt][3] *= scr[3];
      }
#pragma unroll
      for (int ks = 0; ks < 2; ++ks) {
        unsigned int E0D0 = cvtpk_bf16(pvv[ks * 2][0], pvv[ks * 2][1]);
        unsigned int E0D1 = cvtpk_bf16(pvv[ks * 2][2], pvv[ks * 2][3]);
        unsigned int E1D0 = cvtpk_bf16(pvv[ks * 2 + 1][0], pvv[ks * 2 + 1][1]);
        unsigned int E1D1 = cvtpk_bf16(pvv[ks * 2 + 1][2], pvv[ks * 2 + 1][3]);
        int src0 = ((lane >> 4) & 1) * 32 + cl;
        int src1 = src0 + 16;
        unsigned int a0 = (unsigned int)__shfl((int)E0D0, src0, 64);
        unsigned int a1 = (unsigned int)__shfl((int)E0D1, src0, 64);
        unsigned int a2 = (unsigned int)__shfl((int)E0D0, src1, 64);
        unsigned int a3 = (unsigned int)__shfl((int)E0D1, src1, 64);
        unsigned int b0 = (unsigned int)__shfl((int)E1D0, src0, 64);
        unsigned int b1 = (unsigned int)__shfl((int)E1D1, src0, 64);
        unsigned int b2 = (unsigned int)__shfl((int)E1D0, src1, 64);
        unsigned int b3 = (unsigned int)__shfl((int)E1D1, src1, 64);
        bool hi = lane >= 32;
        union { unsigned int u[4]; bf16x8 v; } af;
        af.u[0] = hi ? b0 : a0;
        af.u[1] = hi ? b1 : a1;
        af.u[2] = hi ? b2 : a2;
        af.u[3] = hi ? b3 : a3;
#pragma unroll
        for (int dt = 0; dt < 4; ++dt) {
          int d = dt * 16 + cl;
          bf16x8 vf = *(const bf16x8*)(Vlds + d * 64 + (((ks * 4 + g) ^ (d & 7)) * 8));
          oacc[qt][dt] = MFMA_BF16(af.v, vf, oacc[qt][dt]);
        }
      }
    }
  }

#pragma unroll
  for (int qt = 0; qt < 2; ++qt) {
    float lr[4];
#pragma unroll
    for (int r = 0; r < 4; ++r) lr[r] = 1.f / __shfl(lrun[qt], g * 4 + r, 64);
#pragma unroll
    for (int dt = 0; dt < 4; ++dt)
#pragma unroll
      for (int r = 0; r < 4; ++r) {
        int row = c * 256 + wq * 32 + qt * 16 + g * 4 + r;
        Aout[(bs + row) * D_MODEL + h * DH + dt * 16 + cl] =
            f2bf_bits(oacc[qt][dt][r] * lr[r]);
      }
  }
}

// ---------------------------------------------------------------------------
// global row 0 attends to all S keys (QKV strided; Q prescaled).
// ---------------------------------------------------------------------------
__global__ __launch_bounds__(256) void global_attn_kernel(
    const unsigned short* __restrict__ Q, const unsigned short* __restrict__ K,
    const unsigned short* __restrict__ V, const int* __restrict__ att,
    unsigned short* __restrict__ Aout) {
  int h = blockIdx.x, b = blockIdx.y;
  int t = threadIdx.x;
  __shared__ float sc[S_LEN];
  __shared__ float q0[64];
  __shared__ float red[4];
  __shared__ float part[4][64];
  const size_t bs = (size_t)b * S_LEN;
  if (t < 64) q0[t] = bf2f(Q[bs * QSTR + h * DH + t]);
  __syncthreads();
  float lmax = -1e30f;
  for (int s = t; s < S_LEN; s += 256) {
    const unsigned short* kp = K + (bs + s) * QSTR + h * DH;
    float acc = 0.f;
#pragma unroll
    for (int cc = 0; cc < 8; ++cc) {
      uint4 u = *(const uint4*)(kp + cc * 8);
      const unsigned int* uu = (const unsigned int*)&u;
#pragma unroll
      for (int w2 = 0; w2 < 4; ++w2) {
        unsigned int x = uu[w2];
        acc += q0[cc * 8 + w2 * 2] * __uint_as_float(x << 16);
        acc += q0[cc * 8 + w2 * 2 + 1] * __uint_as_float(x & 0xffff0000u);
      }
    }
    acc = (att[b * S_LEN + s] > 0) ? acc : -1e9f;
    sc[s] = acc;
    lmax = fmaxf(lmax, acc);
  }
  float M = blk_max256(lmax, red);
  float lsum = 0.f;
  for (int s = t; s < S_LEN; s += 256) {
    float p = __expf(sc[s] - M);
    sc[s] = p;
    lsum += p;
  }
  float L = blk_sum256(lsum, red);
  int d = t & 63, chunk = t >> 6;
  float acc2 = 0.f;
  for (int s = chunk * 1024; s < (chunk + 1) * 1024; ++s)
    acc2 += sc[s] * bf2f(V[(bs + s) * QSTR + h * DH + d]);
  part[chunk][d] = acc2;
  __syncthreads();
  if (t < 64) {
    float v = (part[0][t] + part[1][t] + part[2][t] + part[3][t]) / L;
    Aout[bs * D_MODEL + h * DH + t] = f2bf_bits(v);
  }
}

// ---------------------------------------------------------------------------
// masked mean-pool, two stages
// ---------------------------------------------------------------------------
__global__ __launch_bounds__(256) void pool1_kernel(
    const float* __restrict__ X, const int* __restrict__ att,
    float* __restrict__ ppart) {
  int sb = blockIdx.x, b = blockIdx.y, t = threadIdx.x;
  float a0 = 0.f, a1 = 0.f, a2 = 0.f;
  for (int s = sb * 256; s < sb * 256 + 256; ++s) {
    float a = (float)att[b * S_LEN + s];
    const float* xp = X + ((size_t)b * S_LEN + s) * D_MODEL;
    a0 += xp[t] * a; a1 += xp[t + 256] * a; a2 += xp[t + 512] * a;
  }
  float* pp = ppart + ((size_t)b * 16 + sb) * D_MODEL;
  pp[t] = a0; pp[t + 256] = a1; pp[t + 512] = a2;
}

__global__ __launch_bounds__(256) void pool2_kernel(
    const float* __restrict__ ppart, const int* __restrict__ att,
    float* __restrict__ pooled) {
  int b = blockIdx.x, t = threadIdx.x;
  float a0 = 0.f, a1 = 0.f, a2 = 0.f;
  for (int sb = 0; sb < 16; ++sb) {
    const float* pp = ppart + ((size_t)b * 16 + sb) * D_MODEL;
    a0 += pp[t]; a1 += pp[t + 256]; a2 += pp[t + 512];
  }
  float cnt = 0.f;
  for (int s = 0; s < S_LEN; ++s) cnt += (float)att[b * S_LEN + s];
  cnt = fmaxf(cnt, 1e-9f);
  pooled[b * D_MODEL + t]       = a0 / cnt;
  pooled[b * D_MODEL + t + 256] = a1 / cnt;
  pooled[b * D_MODEL + t + 512] = a2 / cnt;
}

// ---------------------------------------------------------------------------
// head: h = relu(pooled @ Wh1 + bh1); out = sigmoid(h @ Wh2 + bh2) * 4
// ---------------------------------------------------------------------------
__global__ __launch_bounds__(256) void head_kernel(
    const float* __restrict__ pooled, const float* __restrict__ Wh1,
    const float* __restrict__ bh1, const float* __restrict__ Wh2,
    const float* __restrict__ bh2, float* __restrict__ out) {
  __shared__ float hbuf[2][256];
  int t = threadIdx.x;
  for (int b = 0; b < 2; ++b) {
    float acc = bh1[t];
    for (int d = 0; d < D_MODEL; ++d) acc += pooled[b * D_MODEL + d] * Wh1[d * 256 + t];
    hbuf[b][t] = fmaxf(acc, 0.f);
  }
  __syncthreads();
  if (t < 28) {
    int b = t / 14, j = t % 14;
    float acc = bh2[j];
    for (int i = 0; i < 256; ++i) acc += hbuf[b][i] * Wh2[i * 14 + j];
    out[t] = 4.f / (1.f + __expf(-acc));
  }
}

extern "C" void kernel_launch(void* const* d_in, const int* in_sizes, int n_in,
                              void* d_out, int out_size, void* d_ws,
                              size_t ws_size, hipStream_t stream) {
  const int* ids    = (const int*)d_in[0];
  const int* att    = (const int*)d_in[1];
  const float* wemb = (const float*)d_in[2];
  const float* pemb = (const float*)d_in[3];
  const float* elng = (const float*)d_in[4];
  const float* elnb = (const float*)d_in[5];
  const float* Wq   = (const float*)d_in[6];
  const float* bq   = (const float*)d_in[7];
  const float* Wk   = (const float*)d_in[8];
  const float* bk   = (const float*)d_in[9];
  const float* Wv   = (const float*)d_in[10];
  const float* bv   = (const float*)d_in[11];
  const float* Wo   = (const float*)d_in[12];
  const float* bo   = (const float*)d_in[13];
  const float* ln1g = (const float*)d_in[14];
  const float* ln1b = (const float*)d_in[15];
  const float* Wf1  = (const float*)d_in[16];
  const float* bf1  = (const float*)d_in[17];
  const float* Wf2  = (const float*)d_in[18];
  const float* bf2  = (const float*)d_in[19];
  const float* ln2g = (const float*)d_in[20];
  const float* ln2b = (const float*)d_in[21];
  const float* Wh1  = (const float*)d_in[22];
  const float* bh1  = (const float*)d_in[23];
  const float* Wh2  = (const float*)d_in[24];
  const float* bh2  = (const float*)d_in[25];

  const int M = BATCH * S_LEN;  // 8192
  float* ws = (float*)d_ws;
  float* X  = ws;                                           // [0, 6291456)
  float* T  = ws + 6291456;                                 // [.., 12582912)
  unsigned short* QKV = (unsigned short*)(ws + 12582912);   // 18874368 shorts
  unsigned short* Vt  = (unsigned short*)(ws + 22020096);   // 3145728 shorts
  unsigned short* FFbf = QKV;                               // overlays QKV+Vt+part of Abbf
  unsigned short* Abbf = (unsigned short*)(ws + 23592960);  // 6291456 shorts
  unsigned short* Xbf  = (unsigned short*)(ws + 26738688);  // 6291456 shorts
  unsigned short* Wbf  = (unsigned short*)(ws + 29884416);  // 14155776 shorts
  float* pooled = ws + 36962304;
  float* ppart  = ws + 36963840;

  wconv_kernel<<<13824, 256, 0, stream>>>(Wq, Wk, Wv, Wo, Wf1, Wf2, Wbf);
  embed_ln_kernel<<<M, 256, 0, stream>>>(ids, wemb, pemb, elng, elnb, X, Xbf);

  for (int l = 0; l < NLAYER; ++l) {
    const unsigned short* wqkv = Wbf + (size_t)l * 7077888;   // rows 0..2303 = q,k,v
    const unsigned short* wot  = wqkv + 1769472;
    const unsigned short* wf1t = wqkv + 2359296;
    const unsigned short* wf2t = wqkv + 4718592;

    // fused QKV: N = 2304
    gemm_bf16<4><<<dim3(18, 64), 256, 0, stream>>>(
        Xbf, wqkv, bq + l * D_MODEL, bk + l * D_MODEL, bv + l * D_MODEL,
        nullptr, QKV, M, QSTR, 768);

    vtrans_kernel<<<dim3(64, NHEAD, BATCH), 256, 0, stream>>>(QKV + 1536, Vt);
    band_attn_kernel<<<dim3(16, NHEAD, BATCH), 512, 0, stream>>>(
        QKV, QKV + 768, QKV + 1536, Vt, att, Abbf);
    global_attn_kernel<<<dim3(NHEAD, BATCH), 256, 0, stream>>>(
        QKV, QKV + 768, QKV + 1536, att, Abbf);

    gemm_bf16<2><<<dim3(6, 64), 256, 0, stream>>>(
        Abbf, wot, bo + l * D_MODEL, nullptr, nullptr, X, T, M, 768, 768);
    ln_kernel<<<M, 256, 0, stream>>>(T, ln1g + l * D_MODEL, ln1b + l * D_MODEL, X, Xbf);

    gemm_bf16<1><<<dim3(24, 64), 256, 0, stream>>>(
        Xbf, wf1t, bf1 + l * DFF, nullptr, nullptr, nullptr, FFbf, M, DFF, 768);
    gemm_bf16<2><<<dim3(6, 64), 256, 0, stream>>>(
        FFbf, wf2t, bf2 + l * D_MODEL, nullptr, nullptr, X, T, M, 768, DFF);
    ln_kernel<<<M, 256, 0, stream>>>(T, ln2g + l * D_MODEL, ln2b + l * D_MODEL, X, Xbf);
  }

  pool1_kernel<<<dim3(16, BATCH), 256, 0, stream>>>(X, att, ppart);
  pool2_kernel<<<BATCH, 256, 0, stream>>>(ppart, att, pooled);
  head_kernel<<<1, 256, 0, stream>>>(pooled, Wh1, bh1, Wh2, bh2, (float*)d_out);
}

// Round 5
// 876.136 us; speedup vs baseline: 5.3293x; 1.1881x over previous
//
#include <hip/hip_runtime.h>
#include <hip/hip_bf16.h>
#include <math.h>

#define S_LEN 4096
#define D_MODEL 768
#define NHEAD 12
#define DH 64
#define NLAYER 2
#define DFF 3072
#define BATCH 2
#define QSTR 2304   // fused QKV row stride

typedef __attribute__((ext_vector_type(8))) __bf16 bf16x8;
typedef __attribute__((ext_vector_type(4))) float f32x4;

__device__ __forceinline__ unsigned short f2bf_bits(float f) {
  unsigned int u = __float_as_uint(f);
  unsigned int r = (u + 0x7fffu + ((u >> 16) & 1u)) >> 16;
  return (unsigned short)r;
}

__device__ __forceinline__ float bf2f(unsigned short u) {
  return __uint_as_float(((unsigned int)u) << 16);
}

__device__ __forceinline__ unsigned int cvtpk_bf16(float lo, float hi) {
  unsigned int d;
  asm("v_cvt_pk_bf16_f32 %0, %1, %2" : "=v"(d) : "v"(lo), "v"(hi));
  return d;
}

#define ASYNC_COPY16(gsrc, ldst)                                       \
  __builtin_amdgcn_global_load_lds(                                    \
      (const __attribute__((address_space(1))) void*)(gsrc),           \
      (__attribute__((address_space(3))) void*)(ldst), 16, 0, 0)

#define MFMA_BF16(a, b, c) __builtin_amdgcn_mfma_f32_16x16x32_bf16(a, b, c, 0, 0, 0)

// ---------------------------------------------------------------------------
// block-wide reductions (256 threads = 4 waves of 64)
// ---------------------------------------------------------------------------
__device__ __forceinline__ float blk_sum256(float v, float* lds) {
#pragma unroll
  for (int off = 32; off > 0; off >>= 1) v += __shfl_down(v, off, 64);
  __syncthreads();
  if ((threadIdx.x & 63) == 0) lds[threadIdx.x >> 6] = v;
  __syncthreads();
  return lds[0] + lds[1] + lds[2] + lds[3];
}

// ---------------------------------------------------------------------------
// weight transpose + fp32->bf16 convert: W[K][N] f32 -> Wt[N][K] bf16
// ---------------------------------------------------------------------------
__global__ __launch_bounds__(256) void wconv_kernel(
    const float* __restrict__ Wq, const float* __restrict__ Wk,
    const float* __restrict__ Wv, const float* __restrict__ Wo,
    const float* __restrict__ Wf1, const float* __restrict__ Wf2,
    unsigned short* __restrict__ Wbf) {
  int id = blockIdx.x;
  const float* src;
  unsigned short* dst;
  int K, N, t;
  if (id < 4608) {
    int m = id / 576;
    t = id % 576;
    int layer = m >> 2, which = m & 3;
    const float* s = (which == 0) ? Wq : (which == 1) ? Wk : (which == 2) ? Wv : Wo;
    src = s + (size_t)layer * 589824;
    dst = Wbf + (size_t)layer * 7077888 + (size_t)which * 589824;
    K = 768; N = 768;
  } else if (id < 9216) {
    int j = id - 4608;
    int layer = j / 2304;
    t = j % 2304;
    src = Wf1 + (size_t)layer * 2359296;
    dst = Wbf + (size_t)layer * 7077888 + 2359296;
    K = 768; N = 3072;
  } else {
    int j = id - 9216;
    int layer = j / 2304;
    t = j % 2304;
    src = Wf2 + (size_t)layer * 2359296;
    dst = Wbf + (size_t)layer * 7077888 + 4718592;
    K = 3072; N = 768;
  }
  int tiles_n = N >> 5;
  int tk = t / tiles_n, tn = t % tiles_n;
  __shared__ float tile[32][33];
  int c = threadIdx.x & 31, r0 = threadIdx.x >> 5;
#pragma unroll
  for (int p = 0; p < 4; ++p) {
    int r = r0 + p * 8;
    tile[r][c] = src[(size_t)(tk * 32 + r) * N + tn * 32 + c];
  }
  __syncthreads();
#pragma unroll
  for (int p = 0; p < 4; ++p) {
    int r = r0 + p * 8;
    dst[(size_t)(tn * 32 + r) * K + tk * 32 + c] = f2bf_bits(tile[c][r]);
  }
}

// ---------------------------------------------------------------------------
// embedding gather + LayerNorm; writes fp32 X and bf16 Xb
// ---------------------------------------------------------------------------
__global__ __launch_bounds__(256) void embed_ln_kernel(
    const int* __restrict__ ids, const float* __restrict__ wemb,
    const float* __restrict__ pemb, const float* __restrict__ g,
    const float* __restrict__ b, float* __restrict__ X,
    unsigned short* __restrict__ Xb) {
  int row = blockIdx.x;
  int s = row % S_LEN;
  int id = ids[row];
  const float* we = wemb + (size_t)id * D_MODEL;
  const float* pe = pemb + (size_t)s * D_MODEL;
  int t = threadIdx.x;
  __shared__ float lds[4];
  float v0 = we[t] + pe[t];
  float v1 = we[t + 256] + pe[t + 256];
  float v2 = we[t + 512] + pe[t + 512];
  float mean = blk_sum256(v0 + v1 + v2, lds) * (1.f / 768.f);
  float d0 = v0 - mean, d1 = v1 - mean, d2 = v2 - mean;
  float var = blk_sum256(d0 * d0 + d1 * d1 + d2 * d2, lds) * (1.f / 768.f);
  float rs = rsqrtf(var + 1e-5f);
  float o0 = d0 * rs * g[t] + b[t];
  float o1 = d1 * rs * g[t + 256] + b[t + 256];
  float o2 = d2 * rs * g[t + 512] + b[t + 512];
  float* xp = X + (size_t)row * D_MODEL;
  xp[t] = o0; xp[t + 256] = o1; xp[t + 512] = o2;
  unsigned short* xb = Xb + (size_t)row * D_MODEL;
  xb[t] = f2bf_bits(o0); xb[t + 256] = f2bf_bits(o1); xb[t + 512] = f2bf_bits(o2);
}

// ---------------------------------------------------------------------------
// LayerNorm: X = LN(T) * g + b ; writes fp32 X and bf16 Xb
// ---------------------------------------------------------------------------
__global__ __launch_bounds__(256) void ln_kernel(
    const float* __restrict__ T, const float* __restrict__ g,
    const float* __restrict__ b, float* __restrict__ X,
    unsigned short* __restrict__ Xb) {
  int row = blockIdx.x;
  const float* tp = T + (size_t)row * D_MODEL;
  int t = threadIdx.x;
  __shared__ float lds[4];
  float v0 = tp[t], v1 = tp[t + 256], v2 = tp[t + 512];
  float mean = blk_sum256(v0 + v1 + v2, lds) * (1.f / 768.f);
  float d0 = v0 - mean, d1 = v1 - mean, d2 = v2 - mean;
  float var = blk_sum256(d0 * d0 + d1 * d1 + d2 * d2, lds) * (1.f / 768.f);
  float rs = rsqrtf(var + 1e-5f);
  float o0 = d0 * rs * g[t] + b[t];
  float o1 = d1 * rs * g[t + 256] + b[t + 256];
  float o2 = d2 * rs * g[t + 512] + b[t + 512];
  float* xp = X + (size_t)row * D_MODEL;
  xp[t] = o0; xp[t + 256] = o1; xp[t + 512] = o2;
  unsigned short* xb = Xb + (size_t)row * D_MODEL;
  xb[t] = f2bf_bits(o0); xb[t + 256] = f2bf_bits(o1); xb[t + 512] = f2bf_bits(o2);
}

// ---------------------------------------------------------------------------
// bf16 MFMA GEMM: C = epilogue(A[MxK] @ Bt[NxK]^T + bias)
// 128x128 tile, BK=32, 4 waves. DEPTH-2 pipeline: 3 LDS buffers, counted
// vmcnt(4) + raw s_barrier (loads span 2 iterations). XCD block swizzle.
// MODE 1: out bf16, +bias0, gelu               (FFN1)
// MODE 2: out f32, +bias0, +Res f32            (O-proj / FFN2)
// MODE 4: out bf16 stride N, 3 bias arrays, cols<768 scaled 1/8 (QKV)
// ---------------------------------------------------------------------------
template <int MODE>
__global__ __launch_bounds__(256) void gemm_bf16(
    const unsigned short* __restrict__ A, const unsigned short* __restrict__ Bt,
    const float* __restrict__ bias0, const float* __restrict__ bias1,
    const float* __restrict__ bias2, const float* __restrict__ Res,
    void* __restrict__ Cout, int M, int N, int K) {
  __shared__ unsigned short Abuf[3][128 * 32];
  __shared__ unsigned short Bbuf[3][128 * 32];
  const int tid = threadIdx.x;
  const int lane = tid & 63, w = tid >> 6;
  const int wm = w >> 1, wn = w & 1;

  const int nbx = gridDim.x;
  const int nwg = nbx * gridDim.y;
  const int orig = blockIdx.y * nbx + blockIdx.x;
  const int wgid = (orig & 7) * (nwg >> 3) + (orig >> 3);
  const int m0 = (wgid / nbx) * 128, n0 = (wgid % nbx) * 128;

  f32x4 acc[4][4];
#pragma unroll
  for (int i = 0; i < 4; ++i)
#pragma unroll
    for (int j = 0; j < 4; ++j) acc[i][j] = (f32x4){0.f, 0.f, 0.f, 0.f};

  // staging: slot s -> row r = s>>2, 16B-chunk c = s&3; SOURCE chunk permuted
  const int s0 = w * 64 + lane, s1 = s0 + 256;
  const int r0 = s0 >> 2, c0 = (s0 & 3) ^ (r0 & 3);
  const int r1 = s1 >> 2, c1 = (s1 & 3) ^ (r1 & 3);
  const unsigned short* gA0 = A + (size_t)(m0 + r0) * K + c0 * 8;
  const unsigned short* gA1 = A + (size_t)(m0 + r1) * K + c1 * 8;
  const unsigned short* gB0 = Bt + (size_t)(n0 + r0) * K + c0 * 8;
  const unsigned short* gB1 = Bt + (size_t)(n0 + r1) * K + c1 * 8;
  const int dA0 = (w * 64) * 8, dA1 = (256 + w * 64) * 8;

  const int frow = lane & 15, kgrp = lane >> 4;
  int aoff[4], boff[4];
#pragma unroll
  for (int i = 0; i < 4; ++i) {
    int ra = wm * 64 + i * 16 + frow;
    int rb = wn * 64 + i * 16 + frow;
    aoff[i] = ra * 32 + ((kgrp ^ (ra & 3)) * 8);
    boff[i] = rb * 32 + ((kgrp ^ (rb & 3)) * 8);
  }

#define STAGE(bsel)                                                       \
  {                                                                       \
    ASYNC_COPY16(gA0, &Abuf[bsel][dA0]);                                  \
    ASYNC_COPY16(gA1, &Abuf[bsel][dA1]);                                  \
    ASYNC_COPY16(gB0, &Bbuf[bsel][dA0]);                                  \
    ASYNC_COPY16(gB1, &Bbuf[bsel][dA1]);                                  \
    gA0 += 32; gA1 += 32; gB0 += 32; gB1 += 32;                           \
  }

  const int nk = K >> 5;
  STAGE(0);
  if (nk > 1) STAGE(1);
  asm volatile("s_waitcnt vmcnt(4)" ::: "memory");   // tile 0 landed
  __builtin_amdgcn_s_barrier();
  __builtin_amdgcn_sched_barrier(0);

  int cur = 0;
  for (int kt = 0; kt < nk; ++kt) {
    if (kt + 2 < nk) {
      int nxt = cur + 2;
      if (nxt >= 3) nxt -= 3;
      STAGE(nxt);                                    // tile kt+2, 2-deep
    }
    bf16x8 av[4], bv[4];
#pragma unroll
    for (int i = 0; i < 4; ++i) av[i] = *(const bf16x8*)(&Abuf[cur][aoff[i]]);
#pragma unroll
    for (int j = 0; j < 4; ++j) bv[j] = *(const bf16x8*)(&Bbuf[cur][boff[j]]);
#pragma unroll
    for (int i = 0; i < 4; ++i)
#pragma unroll
      for (int j = 0; j < 4; ++j)
        acc[i][j] = MFMA_BF16(av[i], bv[j], acc[i][j]);
    if (kt + 1 < nk) {
      if (kt + 2 < nk)
        asm volatile("s_waitcnt vmcnt(4)" ::: "memory");   // tile kt+1 landed
      else
        asm volatile("s_waitcnt vmcnt(0)" ::: "memory");
      __builtin_amdgcn_s_barrier();
      __builtin_amdgcn_sched_barrier(0);
    }
    cur = (cur == 2) ? 0 : cur + 1;
  }
#undef STAGE

#pragma unroll
  for (int i = 0; i < 4; ++i) {
#pragma unroll
    for (int j = 0; j < 4; ++j) {
      int grb = m0 + wm * 64 + i * 16 + (lane >> 4) * 4;
      int gc = n0 + wn * 64 + j * 16 + (lane & 15);
      float bsv;
      if (MODE == 4)
        bsv = (gc < 768) ? bias0[gc] : (gc < 1536) ? bias1[gc - 768] : bias2[gc - 1536];
      else
        bsv = bias0[gc];
#pragma unroll
      for (int r = 0; r < 4; ++r) {
        int gr = grb + r;
        float v = acc[i][j][r] + bsv;
        if (MODE == 1) {
          float x = v;
          float th = tanhf(0.7978845608028654f * (x + 0.044715f * x * x * x));
          v = 0.5f * x * (1.f + th);
        }
        if (MODE == 4 && gc < 768) v *= 0.125f;
        if (MODE == 2) v += Res[(size_t)gr * N + gc];
        if (MODE == 1 || MODE == 4)
          ((unsigned short*)Cout)[(size_t)gr * N + gc] = f2bf_bits(v);
        else
          ((float*)Cout)[(size_t)gr * N + gc] = v;
      }
    }
  }
}

// ---------------------------------------------------------------------------
// V transpose per (b,h): QKV V-cols -> Vt[(b*12+h)*64 + d][4096] bf16
// ---------------------------------------------------------------------------
__global__ __launch_bounds__(256) void vtrans_kernel(
    const unsigned short* __restrict__ Vsrc, unsigned short* __restrict__ Vt) {
  int kb = blockIdx.x, h = blockIdx.y, b = blockIdx.z;
  int k0 = kb * 64;
  const size_t bs = (size_t)b * S_LEN;
  const size_t bh = (size_t)(b * NHEAD + h);
  __shared__ unsigned short tile[64][72];
  int tid = threadIdx.x;
#pragma unroll
  for (int p = 0; p < 2; ++p) {
    int idx = p * 256 + tid;
    int key = idx >> 3, ch = idx & 7;
    bf16x8 v = *(const bf16x8*)(Vsrc + (bs + k0 + key) * QSTR + h * DH + ch * 8);
    *(bf16x8*)&tile[key][ch * 8] = v;
  }
  __syncthreads();
#pragma unroll
  for (int p = 0; p < 2; ++p) {
    int idx = p * 256 + tid;
    int d = idx >> 3, kc = idx & 7;
    unsigned int w0 = tile[kc * 8 + 0][d] | ((unsigned int)tile[kc * 8 + 1][d] << 16);
    unsigned int w1 = tile[kc * 8 + 2][d] | ((unsigned int)tile[kc * 8 + 3][d] << 16);
    unsigned int w2 = tile[kc * 8 + 4][d] | ((unsigned int)tile[kc * 8 + 5][d] << 16);
    unsigned int w3 = tile[kc * 8 + 6][d] | ((unsigned int)tile[kc * 8 + 7][d] << 16);
    uint4 out = make_uint4(w0, w1, w2, w3);
    *(uint4*)(Vt + (bh * 64 + d) * S_LEN + k0 + kc * 8) = out;
  }
}

// ---------------------------------------------------------------------------
// MFMA band attention + fused global-row-0 path.
// grid (17, H=12, B=2), 512 threads = 8 waves. Blocks c<16: band chunks
// (skip writing row 0). Block c==16: row 0 attends to all S keys.
// ---------------------------------------------------------------------------
__global__ __launch_bounds__(512) void band_attn_kernel(
    const unsigned short* __restrict__ Qg, const unsigned short* __restrict__ Kgb,
    const unsigned short* __restrict__ Vgb, const unsigned short* __restrict__ Vt,
    const int* __restrict__ att, unsigned short* __restrict__ Aout) {
  const int c = blockIdx.x, h = blockIdx.y, b = blockIdx.z;
  const int tid = threadIdx.x;
  const int lane = tid & 63, wq = tid >> 6;
  const int g = lane >> 4, cl = lane & 15;
  const size_t bs = (size_t)b * S_LEN;
  const size_t bh = (size_t)(b * NHEAD + h);

  __shared__ __align__(16) char smem[18944];

  if (c == 16) {
    // ---- global row 0: 512-thread full-S scan ----
    float* sc = (float*)smem;                  // 4096
    float* q0 = sc + S_LEN;                    // 64
    float* red = q0 + 64;                      // 8
    float* part = red + 8;                     // 8*64
    if (tid < 64) q0[tid] = bf2f(Qg[bs * QSTR + h * DH + tid]);
    __syncthreads();
    float lmax = -1e30f;
    for (int s = tid; s < S_LEN; s += 512) {
      const unsigned short* kp = Kgb + (bs + s) * QSTR + h * DH;
      float acc = 0.f;
#pragma unroll
      for (int cc = 0; cc < 8; ++cc) {
        uint4 u = *(const uint4*)(kp + cc * 8);
        const unsigned int* uu = (const unsigned int*)&u;
#pragma unroll
        for (int w2 = 0; w2 < 4; ++w2) {
          unsigned int x = uu[w2];
          acc += q0[cc * 8 + w2 * 2] * __uint_as_float(x << 16);
          acc += q0[cc * 8 + w2 * 2 + 1] * __uint_as_float(x & 0xffff0000u);
        }
      }
      acc = (att[b * S_LEN + s] > 0) ? acc : -1e9f;
      sc[s] = acc;
      lmax = fmaxf(lmax, acc);
    }
#pragma unroll
    for (int off = 32; off > 0; off >>= 1) lmax = fmaxf(lmax, __shfl_down(lmax, off, 64));
    __syncthreads();
    if (lane == 0) red[wq] = lmax;
    __syncthreads();
    float M = red[0];
#pragma unroll
    for (int i = 1; i < 8; ++i) M = fmaxf(M, red[i]);
    float lsum = 0.f;
    for (int s = tid; s < S_LEN; s += 512) {
      float p = __expf(sc[s] - M);
      sc[s] = p;
      lsum += p;
    }
#pragma unroll
    for (int off = 32; off > 0; off >>= 1) lsum += __shfl_down(lsum, off, 64);
    __syncthreads();
    if (lane == 0) red[wq] = lsum;
    __syncthreads();
    float L = red[0];
#pragma unroll
    for (int i = 1; i < 8; ++i) L += red[i];
    int d = tid & 63, chunk = tid >> 6;
    float acc2 = 0.f;
    for (int s = chunk * 512; s < (chunk + 1) * 512; ++s)
      acc2 += sc[s] * bf2f(Vgb[(bs + s) * QSTR + h * DH + d]);
    part[chunk * 64 + d] = acc2;
    __syncthreads();
    if (tid < 64) {
      float v = 0.f;
#pragma unroll
      for (int i = 0; i < 8; ++i) v += part[i * 64 + tid];
      Aout[bs * D_MODEL + h * DH + tid] = f2bf_bits(v / L);
    }
    return;
  }

  // ---- band path ----
  unsigned short* Klds = (unsigned short*)smem;           // [key][d] swizzled
  unsigned short* Vlds = Klds + 64 * 64;                  // [d][key] swizzled
  float* kmask = (float*)(Vlds + 64 * 64);

  bf16x8 qf[2][2];
#pragma unroll
  for (int qt = 0; qt < 2; ++qt)
#pragma unroll
    for (int ks = 0; ks < 2; ++ks)
      qf[qt][ks] = *(const bf16x8*)(Qg + (bs + c * 256 + wq * 32 + qt * 16 + cl) * QSTR +
                                    h * DH + ks * 32 + g * 8);

  float mrun[2], lrun[2];
  f32x4 oacc[2][4];
#pragma unroll
  for (int qt = 0; qt < 2; ++qt) {
    float sg = 0.f;
#pragma unroll
    for (int ks = 0; ks < 2; ++ks) {
      bf16x8 k0 = *(const bf16x8*)(Kgb + bs * QSTR + h * DH + ks * 32 + g * 8);
#pragma unroll
      for (int j = 0; j < 8; ++j) sg += (float)qf[qt][ks][j] * (float)k0[j];
    }
    sg += __shfl_xor(sg, 16, 64);
    sg += __shfl_xor(sg, 32, 64);
    mrun[qt] = sg;
    lrun[qt] = 1.f;
  }
#pragma unroll
  for (int dt = 0; dt < 4; ++dt) {
    float v0d = bf2f(Vgb[bs * QSTR + h * DH + dt * 16 + cl]);
    f32x4 vv = {v0d, v0d, v0d, v0d};
    oacc[0][dt] = vv;
    oacc[1][dt] = vv;
  }

  const int jlo = wq * 32, jhi = wq * 32 + 543;

  for (int t = 0; t < 12; ++t) {
    int kabs0 = c * 256 - 256 + t * 64;
    if (kabs0 < 0 || kabs0 >= S_LEN) continue;
    __syncthreads();
    {
      int key = tid >> 3, ch = tid & 7;
      bf16x8 kv = *(const bf16x8*)(Kgb + (bs + kabs0 + key) * QSTR + h * DH + ch * 8);
      *(bf16x8*)(Klds + key * 64 + ((ch ^ (key & 7)) * 8)) = kv;
      bf16x8 vv = *(const bf16x8*)(Vt + (bh * 64 + key) * S_LEN + kabs0 + ch * 8);
      *(bf16x8*)(Vlds + key * 64 + ((ch ^ (key & 7)) * 8)) = vv;
      if (tid < 64) {
        int ka = kabs0 + tid;
        kmask[tid] = (ka >= 1 && att[b * S_LEN + ka] > 0) ? 0.f : -1e9f;
      }
    }
    __syncthreads();
    if (t * 64 + 63 < jlo || t * 64 > jhi) continue;

    f32x4 accs[4][2];
#pragma unroll
    for (int kt = 0; kt < 4; ++kt) {
      accs[kt][0] = (f32x4){0.f, 0.f, 0.f, 0.f};
      accs[kt][1] = (f32x4){0.f, 0.f, 0.f, 0.f};
    }
#pragma unroll
    for (int ks = 0; ks < 2; ++ks) {
      bf16x8 kf[4];
#pragma unroll
      for (int kt = 0; kt < 4; ++kt) {
        int key = kt * 16 + cl;
        kf[kt] = *(const bf16x8*)(Klds + key * 64 + (((ks * 4 + g) ^ (key & 7)) * 8));
      }
#pragma unroll
      for (int kt = 0; kt < 4; ++kt) {
        accs[kt][0] = MFMA_BF16(kf[kt], qf[0][ks], accs[kt][0]);
        accs[kt][1] = MFMA_BF16(kf[kt], qf[1][ks], accs[kt][1]);
      }
    }

#pragma unroll
    for (int qt = 0; qt < 2; ++qt) {
      int iq = wq * 32 + qt * 16 + cl;
      int relbase = t * 64 - iq;
      float pvv[4][4];
      float tmax = -1e30f;
#pragma unroll
      for (int kt = 0; kt < 4; ++kt)
#pragma unroll
        for (int r = 0; r < 4; ++r) {
          int key = kt * 16 + g * 4 + r;
          int rel = relbase + key;
          float x = accs[kt][qt][r] + kmask[key];
          x = (rel >= 0 && rel <= 512) ? x : -1e9f;
          pvv[kt][r] = x;
          tmax = fmaxf(tmax, x);
        }
      tmax = fmaxf(tmax, __shfl_xor(tmax, 16, 64));
      tmax = fmaxf(tmax, __shfl_xor(tmax, 32, 64));
      float mnew = fmaxf(mrun[qt], tmax);
      float scale = __expf(mrun[qt] - mnew);
      mrun[qt] = mnew;
      float psum = 0.f;
#pragma unroll
      for (int kt = 0; kt < 4; ++kt)
#pragma unroll
        for (int r = 0; r < 4; ++r) {
          float p = __expf(pvv[kt][r] - mnew);
          pvv[kt][r] = p;
          psum += p;
        }
      psum += __shfl_xor(psum, 16, 64);
      psum += __shfl_xor(psum, 32, 64);
      lrun[qt] = lrun[qt] * scale + psum;
      float scr[4];
#pragma unroll
      for (int r = 0; r < 4; ++r) scr[r] = __shfl(scale, g * 4 + r, 64);
#pragma unroll
      for (int dt = 0; dt < 4; ++dt) {
        oacc[qt][dt][0] *= scr[0];
        oacc[qt][dt][1] *= scr[1];
        oacc[qt][dt][2] *= scr[2];
        oacc[qt][dt][3] *= scr[3];
      }
#pragma unroll
      for (int ks = 0; ks < 2; ++ks) {
        unsigned int E0D0 = cvtpk_bf16(pvv[ks * 2][0], pvv[ks * 2][1]);
        unsigned int E0D1 = cvtpk_bf16(pvv[ks * 2][2], pvv[ks * 2][3]);
        unsigned int E1D0 = cvtpk_bf16(pvv[ks * 2 + 1][0], pvv[ks * 2 + 1][1]);
        unsigned int E1D1 = cvtpk_bf16(pvv[ks * 2 + 1][2], pvv[ks * 2 + 1][3]);
        int src0 = ((lane >> 4) & 1) * 32 + cl;
        int src1 = src0 + 16;
        unsigned int a0 = (unsigned int)__shfl((int)E0D0, src0, 64);
        unsigned int a1 = (unsigned int)__shfl((int)E0D1, src0, 64);
        unsigned int a2 = (unsigned int)__shfl((int)E0D0, src1, 64);
        unsigned int a3 = (unsigned int)__shfl((int)E0D1, src1, 64);
        unsigned int b0 = (unsigned int)__shfl((int)E1D0, src0, 64);
        unsigned int b1 = (unsigned int)__shfl((int)E1D1, src0, 64);
        unsigned int b2 = (unsigned int)__shfl((int)E1D0, src1, 64);
        unsigned int b3 = (unsigned int)__shfl((int)E1D1, src1, 64);
        bool hi = lane >= 32;
        union { unsigned int u[4]; bf16x8 v; } af;
        af.u[0] = hi ? b0 : a0;
        af.u[1] = hi ? b1 : a1;
        af.u[2] = hi ? b2 : a2;
        af.u[3] = hi ? b3 : a3;
#pragma unroll
        for (int dt = 0; dt < 4; ++dt) {
          int d = dt * 16 + cl;
          bf16x8 vf = *(const bf16x8*)(Vlds + d * 64 + (((ks * 4 + g) ^ (d & 7)) * 8));
          oacc[qt][dt] = MFMA_BF16(af.v, vf, oacc[qt][dt]);
        }
      }
    }
  }

#pragma unroll
  for (int qt = 0; qt < 2; ++qt) {
    float lr[4];
#pragma unroll
    for (int r = 0; r < 4; ++r) lr[r] = 1.f / __shfl(lrun[qt], g * 4 + r, 64);
#pragma unroll
    for (int dt = 0; dt < 4; ++dt)
#pragma unroll
      for (int r = 0; r < 4; ++r) {
        int row = c * 256 + wq * 32 + qt * 16 + g * 4 + r;
        if (row != 0)    // row 0 is owned by the global path (c==16)
          Aout[(bs + row) * D_MODEL + h * DH + dt * 16 + cl] =
              f2bf_bits(oacc[qt][dt][r] * lr[r]);
      }
  }
}

// ---------------------------------------------------------------------------
// masked mean-pool, two stages
// ---------------------------------------------------------------------------
__global__ __launch_bounds__(256) void pool1_kernel(
    const float* __restrict__ X, const int* __restrict__ att,
    float* __restrict__ ppart) {
  int sb = blockIdx.x, b = blockIdx.y, t = threadIdx.x;
  float a0 = 0.f, a1 = 0.f, a2 = 0.f;
  for (int s = sb * 256; s < sb * 256 + 256; ++s) {
    float a = (float)att[b * S_LEN + s];
    const float* xp = X + ((size_t)b * S_LEN + s) * D_MODEL;
    a0 += xp[t] * a; a1 += xp[t + 256] * a; a2 += xp[t + 512] * a;
  }
  float* pp = ppart + ((size_t)b * 16 + sb) * D_MODEL;
  pp[t] = a0; pp[t + 256] = a1; pp[t + 512] = a2;
}

__global__ __launch_bounds__(256) void pool2_kernel(
    const float* __restrict__ ppart, const int* __restrict__ att,
    float* __restrict__ pooled) {
  int b = blockIdx.x, t = threadIdx.x;
  float a0 = 0.f, a1 = 0.f, a2 = 0.f;
  for (int sb = 0; sb < 16; ++sb) {
    const float* pp = ppart + ((size_t)b * 16 + sb) * D_MODEL;
    a0 += pp[t]; a1 += pp[t + 256]; a2 += pp[t + 512];
  }
  float cnt = 0.f;
  for (int s = 0; s < S_LEN; ++s) cnt += (float)att[b * S_LEN + s];
  cnt = fmaxf(cnt, 1e-9f);
  pooled[b * D_MODEL + t]       = a0 / cnt;
  pooled[b * D_MODEL + t + 256] = a1 / cnt;
  pooled[b * D_MODEL + t + 512] = a2 / cnt;
}

// ---------------------------------------------------------------------------
// head: h = relu(pooled @ Wh1 + bh1); out = sigmoid(h @ Wh2 + bh2) * 4
// ---------------------------------------------------------------------------
__global__ __launch_bounds__(256) void head_kernel(
    const float* __restrict__ pooled, const float* __restrict__ Wh1,
    const float* __restrict__ bh1, const float* __restrict__ Wh2,
    const float* __restrict__ bh2, float* __restrict__ out) {
  __shared__ float hbuf[2][256];
  int t = threadIdx.x;
  for (int b = 0; b < 2; ++b) {
    float acc = bh1[t];
    for (int d = 0; d < D_MODEL; ++d) acc += pooled[b * D_MODEL + d] * Wh1[d * 256 + t];
    hbuf[b][t] = fmaxf(acc, 0.f);
  }
  __syncthreads();
  if (t < 28) {
    int b = t / 14, j = t % 14;
    float acc = bh2[j];
    for (int i = 0; i < 256; ++i) acc += hbuf[b][i] * Wh2[i * 14 + j];
    out[t] = 4.f / (1.f + __expf(-acc));
  }
}

extern "C" void kernel_launch(void* const* d_in, const int* in_sizes, int n_in,
                              void* d_out, int out_size, void* d_ws,
                              size_t ws_size, hipStream_t stream) {
  const int* ids    = (const int*)d_in[0];
  const int* att    = (const int*)d_in[1];
  const float* wemb = (const float*)d_in[2];
  const float* pemb = (const float*)d_in[3];
  const float* elng = (const float*)d_in[4];
  const float* elnb = (const float*)d_in[5];
  const float* Wq   = (const float*)d_in[6];
  const float* bq   = (const float*)d_in[7];
  const float* Wk   = (const float*)d_in[8];
  const float* bk   = (const float*)d_in[9];
  const float* Wv   = (const float*)d_in[10];
  const float* bv   = (const float*)d_in[11];
  const float* Wo   = (const float*)d_in[12];
  const float* bo   = (const float*)d_in[13];
  const float* ln1g = (const float*)d_in[14];
  const float* ln1b = (const float*)d_in[15];
  const float* Wf1  = (const float*)d_in[16];
  const float* bf1  = (const float*)d_in[17];
  const float* Wf2  = (const float*)d_in[18];
  const float* bf2  = (const float*)d_in[19];
  const float* ln2g = (const float*)d_in[20];
  const float* ln2b = (const float*)d_in[21];
  const float* Wh1  = (const float*)d_in[22];
  const float* bh1  = (const float*)d_in[23];
  const float* Wh2  = (const float*)d_in[24];
  const float* bh2  = (const float*)d_in[25];

  const int M = BATCH * S_LEN;  // 8192
  float* ws = (float*)d_ws;
  float* X  = ws;
  float* T  = ws + 6291456;
  unsigned short* QKV = (unsigned short*)(ws + 12582912);
  unsigned short* Vt  = (unsigned short*)(ws + 22020096);
  unsigned short* FFbf = QKV;
  unsigned short* Abbf = (unsigned short*)(ws + 23592960);
  unsigned short* Xbf  = (unsigned short*)(ws + 26738688);
  unsigned short* Wbf  = (unsigned short*)(ws + 29884416);
  float* pooled = ws + 36962304;
  float* ppart  = ws + 36963840;

  wconv_kernel<<<13824, 256, 0, stream>>>(Wq, Wk, Wv, Wo, Wf1, Wf2, Wbf);
  embed_ln_kernel<<<M, 256, 0, stream>>>(ids, wemb, pemb, elng, elnb, X, Xbf);

  for (int l = 0; l < NLAYER; ++l) {
    const unsigned short* wqkv = Wbf + (size_t)l * 7077888;
    const unsigned short* wot  = wqkv + 1769472;
    const unsigned short* wf1t = wqkv + 2359296;
    const unsigned short* wf2t = wqkv + 4718592;

    gemm_bf16<4><<<dim3(18, 64), 256, 0, stream>>>(
        Xbf, wqkv, bq + l * D_MODEL, bk + l * D_MODEL, bv + l * D_MODEL,
        nullptr, QKV, M, QSTR, 768);

    vtrans_kernel<<<dim3(64, NHEAD, BATCH), 256, 0, stream>>>(QKV + 1536, Vt);
    band_attn_kernel<<<dim3(17, NHEAD, BATCH), 512, 0, stream>>>(
        QKV, QKV + 768, QKV + 1536, Vt, att, Abbf);

    gemm_bf16<2><<<dim3(6, 64), 256, 0, stream>>>(
        Abbf, wot, bo + l * D_MODEL, nullptr, nullptr, X, T, M, 768, 768);
    ln_kernel<<<M, 256, 0, stream>>>(T, ln1g + l * D_MODEL, ln1b + l * D_MODEL, X, Xbf);

    gemm_bf16<1><<<dim3(24, 64), 256, 0, stream>>>(
        Xbf, wf1t, bf1 + l * DFF, nullptr, nullptr, nullptr, FFbf, M, DFF, 768);
    gemm_bf16<2><<<dim3(6, 64), 256, 0, stream>>>(
        FFbf, wf2t, bf2 + l * D_MODEL, nullptr, nullptr, X, T, M, 768, DFF);
    ln_kernel<<<M, 256, 0, stream>>>(T, ln2g + l * D_MODEL, ln2b + l * D_MODEL, X, Xbf);
  }

  pool1_kernel<<<dim3(16, BATCH), 256, 0, stream>>>(X, att, ppart);
  pool2_kernel<<<BATCH, 256, 0, stream>>>(ppart, att, pooled);
  head_kernel<<<1, 256, 0, stream>>>(pooled, Wh1, bh1, Wh2, bh2, (float*)d_out);
}